// Round 6
// baseline (1200.810 us; speedup 1.0000x reference)
//
#include <hip/hip_runtime.h>

#define NN 50000
#define NE 800000
#define NG 512
#define TPB 256
#define BN_EPS 1e-5f
#define GEMM_NBLK 782   // ceil(NN/64)
#define EDGE_BLKS 3125  // NE/TPB exactly
#define FILL_P 8
#define FILL_CHUNK 6250  // NN/FILL_P

__device__ __forceinline__ float bf2f(unsigned short u) {
  return __uint_as_float(((unsigned)u) << 16);
}
__device__ __forceinline__ unsigned short f2bf(float f) {
  unsigned u = __float_as_uint(f);
  u += 0x7FFFu + ((u >> 16) & 1u);  // round-to-nearest-even
  return (unsigned short)(u >> 16);
}

__global__ void k_zero(int* __restrict__ p, int n) {
  int i = blockIdx.x * TPB + threadIdx.x;
  if (i < n) p[i] = 0;
}

__global__ void k_hist(const int* __restrict__ dst, int* __restrict__ counts) {
  int e = blockIdx.x * TPB + threadIdx.x;
  if (e < NE) atomicAdd(&counts[dst[e]], 1);
}

__global__ void k_scan1(const int* __restrict__ counts, int* __restrict__ incl,
                        int* __restrict__ btot) {
  __shared__ int lds[TPB];
  int i = blockIdx.x * TPB + threadIdx.x;
  int v = (i < NN) ? counts[i] : 0;
  lds[threadIdx.x] = v;
  __syncthreads();
  for (int off = 1; off < TPB; off <<= 1) {
    int t = (threadIdx.x >= off) ? lds[threadIdx.x - off] : 0;
    __syncthreads();
    lds[threadIdx.x] += t;
    __syncthreads();
  }
  if (i < NN) incl[i] = lds[threadIdx.x];
  if (threadIdx.x == TPB - 1) btot[blockIdx.x] = lds[TPB - 1];
}

__global__ void k_scan2(int* __restrict__ btot, int nb) {
  __shared__ int lds[TPB];
  int t = (threadIdx.x < nb) ? btot[threadIdx.x] : 0;
  int own = t;
  lds[threadIdx.x] = t;
  __syncthreads();
  for (int off = 1; off < TPB; off <<= 1) {
    int u = (threadIdx.x >= off) ? lds[threadIdx.x - off] : 0;
    __syncthreads();
    lds[threadIdx.x] += u;
    __syncthreads();
  }
  btot[threadIdx.x] = lds[threadIdx.x] - own;
}

__global__ void k_scan3(const int* __restrict__ incl, const int* __restrict__ btot,
                        int* __restrict__ row_ptr) {
  int i = blockIdx.x * TPB + threadIdx.x;
  if (i == 0) row_ptr[0] = 0;
  if (i < NN) row_ptr[i + 1] = incl[i] + btot[i >> 8];
}

// counting-sort fill (one-time CSR build; ~45us, deprioritized)
__global__ void k_fill(const int* __restrict__ src, const int* __restrict__ dst,
                       const int* __restrict__ row_ptr, int* __restrict__ fill_pos,
                       int* __restrict__ srcs) {
  int pass = blockIdx.x & 7;
  int e = (blockIdx.x >> 3) * TPB + threadIdx.x;
  int d = dst[e];
  if (d / FILL_CHUNK != pass) return;
  int pos = row_ptr[d] + atomicAdd(&fill_pos[d], 1);
  srcs[pos] = src[e];
}

// Fused aggregate + GEMM1 (+BN1 stats): 64 nodes/block, 256 threads.
// Phase 1: wave w aggregates nodes [r0+16w, r0+16w+16) straight into the LDS
//   A-tile, folding the previous layer's BatchNorm affine:
//     z = sc*(h_self + sum h_src) + (1+deg)*sh      (h gathered as bf16)
//   Layer 0: h implicit = emb[x[n]] (emb 8KB, L1-hot).
// Phase 2: z2[64,128] = A @ W[64,128] + b1, with per-block column sum/sumsq
//   partials of z2 for the following BatchNorm.
template <bool L0>
__global__ __launch_bounds__(TPB) void k_agg_gemm1(
    const unsigned short* __restrict__ h_bf, const int* __restrict__ x,
    const float* __restrict__ emb, const int* __restrict__ row_ptr,
    const int* __restrict__ srcs, const float* __restrict__ bnst,
    const float* __restrict__ W, const float* __restrict__ bias,
    float* __restrict__ z2, float* __restrict__ partials) {
  constexpr int NC = 128, K = 64, LDA = 68;
  constexpr int TX = 32, TY = 8, RT = 8;
  __shared__ float Al[64 * LDA];
  __shared__ float Wl[K * NC];
  const int t = threadIdx.x;
  const int r0 = blockIdx.x * 64;

  {
    const float4* Wg = (const float4*)W;
    float4* Wl4 = (float4*)Wl;
#pragma unroll
    for (int j = 0; j < (K * NC / 4) / TPB; ++j) Wl4[t + j * TPB] = Wg[t + j * TPB];
  }

  const int lane = t & 63, w = t >> 6;
  float sc = 1.f, sh = 0.f;
  if constexpr (!L0) {
    sc = bnst[lane];
    sh = bnst[64 + lane];
  }
  for (int j = 0; j < 16; ++j) {
    int node = r0 + w * 16 + j;
    if (node >= NN) break;  // wave-uniform
    int beg = row_ptr[node], end = row_ptr[node + 1];
    float acc;
    if constexpr (L0)
      acc = emb[x[node] * 64 + lane];
    else
      acc = bf2f(h_bf[(size_t)node * 64 + lane]);
    int e = beg;
    for (; e + 8 <= end; e += 8) {
      int s0 = srcs[e], s1 = srcs[e + 1], s2 = srcs[e + 2], s3 = srcs[e + 3];
      int s4 = srcs[e + 4], s5 = srcs[e + 5], s6 = srcs[e + 6], s7 = srcs[e + 7];
      float v0, v1, v2, v3, v4, v5, v6, v7;
      if constexpr (L0) {
        v0 = emb[x[s0] * 64 + lane]; v1 = emb[x[s1] * 64 + lane];
        v2 = emb[x[s2] * 64 + lane]; v3 = emb[x[s3] * 64 + lane];
        v4 = emb[x[s4] * 64 + lane]; v5 = emb[x[s5] * 64 + lane];
        v6 = emb[x[s6] * 64 + lane]; v7 = emb[x[s7] * 64 + lane];
      } else {
        v0 = bf2f(h_bf[(size_t)s0 * 64 + lane]); v1 = bf2f(h_bf[(size_t)s1 * 64 + lane]);
        v2 = bf2f(h_bf[(size_t)s2 * 64 + lane]); v3 = bf2f(h_bf[(size_t)s3 * 64 + lane]);
        v4 = bf2f(h_bf[(size_t)s4 * 64 + lane]); v5 = bf2f(h_bf[(size_t)s5 * 64 + lane]);
        v6 = bf2f(h_bf[(size_t)s6 * 64 + lane]); v7 = bf2f(h_bf[(size_t)s7 * 64 + lane]);
      }
      acc += ((v0 + v1) + (v2 + v3)) + ((v4 + v5) + (v6 + v7));
    }
    for (; e < end; ++e) {
      if constexpr (L0)
        acc += emb[x[srcs[e]] * 64 + lane];
      else
        acc += bf2f(h_bf[(size_t)srcs[e] * 64 + lane]);
    }
    float zv;
    if constexpr (L0)
      zv = acc;
    else
      zv = sc * acc + (float)(1 + end - beg) * sh;
    Al[(w * 16 + j) * LDA + lane] = zv;
  }
  __syncthreads();

  const int tx = t % TX, ty = t / TX;
  const int c0 = tx * 4;
  float4 b0 = *(const float4*)&bias[c0];
  float acc[RT][4];
#pragma unroll
  for (int i = 0; i < RT; ++i) {
    acc[i][0] = b0.x; acc[i][1] = b0.y; acc[i][2] = b0.z; acc[i][3] = b0.w;
  }
  const float* Ab = &Al[ty * RT * LDA];
#pragma unroll 4
  for (int k4 = 0; k4 < K / 4; ++k4) {
    float4 a[RT];
#pragma unroll
    for (int i = 0; i < RT; ++i) a[i] = *(const float4*)&Ab[i * LDA + k4 * 4];
#pragma unroll
    for (int kk = 0; kk < 4; ++kk) {
      float4 b = *(const float4*)&Wl[(k4 * 4 + kk) * NC + c0];
#pragma unroll
      for (int i = 0; i < RT; ++i) {
        float av = (&a[i].x)[kk];
        acc[i][0] = fmaf(av, b.x, acc[i][0]);
        acc[i][1] = fmaf(av, b.y, acc[i][1]);
        acc[i][2] = fmaf(av, b.z, acc[i][2]);
        acc[i][3] = fmaf(av, b.w, acc[i][3]);
      }
    }
  }
  float s[4] = {0.f, 0.f, 0.f, 0.f}, q[4] = {0.f, 0.f, 0.f, 0.f};
#pragma unroll
  for (int i = 0; i < RT; ++i) {
    int r = r0 + ty * RT + i;
    if (r < NN) {
      *(float4*)&z2[(size_t)r * NC + c0] =
          make_float4(acc[i][0], acc[i][1], acc[i][2], acc[i][3]);
      s[0] += acc[i][0]; q[0] += acc[i][0] * acc[i][0];
      s[1] += acc[i][1]; q[1] += acc[i][1] * acc[i][1];
      s[2] += acc[i][2]; q[2] += acc[i][2] * acc[i][2];
      s[3] += acc[i][3]; q[3] += acc[i][3] * acc[i][3];
    }
  }
  __syncthreads();
  float* Sl = Al;  // 2*TY*NC = 2048 floats <= 64*68
#pragma unroll
  for (int j = 0; j < 4; ++j) {
    Sl[ty * NC + c0 + j] = s[j];
    Sl[TY * NC + ty * NC + c0 + j] = q[j];
  }
  __syncthreads();
  if (t < NC) {
    float ss = 0.f, qq = 0.f;
#pragma unroll
    for (int g = 0; g < TY; ++g) {
      ss += Sl[g * NC + t];
      qq += Sl[TY * NC + g * NC + t];
    }
    partials[blockIdx.x * 2 * NC + t] = ss;
    partials[blockIdx.x * 2 * NC + NC + t] = qq;
  }
}

// GEMM2: h[N,64] = relu( relu(bn1(z2)) @ W[128,64] + b2 )
// OUT_BF16: store h as bf16 (gather source for next layer); stats from f32.
template <bool STATS, bool OUT_BF16>
__global__ __launch_bounds__(TPB) void k_gemm2(const float* __restrict__ in,
                                               const float* __restrict__ W,
                                               const float* __restrict__ bias,
                                               const float* __restrict__ bnst,
                                               void* __restrict__ outp,
                                               float* __restrict__ partials) {
  constexpr int K = 128, NC = 64, LDA = 128;
  constexpr int TX = 16, TY = 16, RT = 4;
  __shared__ float Al[64 * LDA];
  __shared__ float Wl[K * NC];
  const int t = threadIdx.x;
  const int r0 = blockIdx.x * 64;

  {
    const float4* Wg = (const float4*)W;
    float4* Wl4 = (float4*)Wl;
#pragma unroll
    for (int j = 0; j < (K * NC / 4) / TPB; ++j) Wl4[t + j * TPB] = Wg[t + j * TPB];
  }
  {
    int cq = t & 31, rb = t >> 5;
    float4 sc4 = *(const float4*)&bnst[cq * 4];
    float4 sh4 = *(const float4*)&bnst[K + cq * 4];
#pragma unroll
    for (int j = 0; j < 8; ++j) {
      int row = rb + j * 8;
      int r = r0 + row;
      float4 v = make_float4(0.f, 0.f, 0.f, 0.f);
      if (r < NN) {
        v = *(const float4*)&in[(size_t)r * 128 + cq * 4];
        v.x = fmaxf(fmaf(v.x, sc4.x, sh4.x), 0.f);
        v.y = fmaxf(fmaf(v.y, sc4.y, sh4.y), 0.f);
        v.z = fmaxf(fmaf(v.z, sc4.z, sh4.z), 0.f);
        v.w = fmaxf(fmaf(v.w, sc4.w, sh4.w), 0.f);
      }
      *(float4*)&Al[row * LDA + cq * 4] = v;
    }
  }
  __syncthreads();

  const int tx = t % TX, ty = t / TX;
  const int c0 = tx * 4;
  float4 b0 = *(const float4*)&bias[c0];
  float acc[RT][4];
#pragma unroll
  for (int i = 0; i < RT; ++i) {
    acc[i][0] = b0.x; acc[i][1] = b0.y; acc[i][2] = b0.z; acc[i][3] = b0.w;
  }
  const float* Ab = &Al[ty * RT * LDA];
#pragma unroll 4
  for (int k4 = 0; k4 < K / 4; ++k4) {
    float4 a[RT];
#pragma unroll
    for (int i = 0; i < RT; ++i) a[i] = *(const float4*)&Ab[i * LDA + k4 * 4];
#pragma unroll
    for (int kk = 0; kk < 4; ++kk) {
      float4 b = *(const float4*)&Wl[(k4 * 4 + kk) * NC + c0];
#pragma unroll
      for (int i = 0; i < RT; ++i) {
        float av = (&a[i].x)[kk];
        acc[i][0] = fmaf(av, b.x, acc[i][0]);
        acc[i][1] = fmaf(av, b.y, acc[i][1]);
        acc[i][2] = fmaf(av, b.z, acc[i][2]);
        acc[i][3] = fmaf(av, b.w, acc[i][3]);
      }
    }
  }
  float s[4] = {0.f, 0.f, 0.f, 0.f}, q[4] = {0.f, 0.f, 0.f, 0.f};
#pragma unroll
  for (int i = 0; i < RT; ++i) {
    int r = r0 + ty * RT + i;
    if (r < NN) {
      float ox = fmaxf(acc[i][0], 0.f), oy = fmaxf(acc[i][1], 0.f);
      float oz = fmaxf(acc[i][2], 0.f), ow = fmaxf(acc[i][3], 0.f);
      if constexpr (OUT_BF16) {
        ushort4 o = make_ushort4(f2bf(ox), f2bf(oy), f2bf(oz), f2bf(ow));
        *(ushort4*)&((unsigned short*)outp)[(size_t)r * NC + c0] = o;
      } else {
        *(float4*)&((float*)outp)[(size_t)r * NC + c0] = make_float4(ox, oy, oz, ow);
      }
      if constexpr (STATS) {
        s[0] += ox; q[0] += ox * ox;
        s[1] += oy; q[1] += oy * oy;
        s[2] += oz; q[2] += oz * oz;
        s[3] += ow; q[3] += ow * ow;
      }
    }
  }
  if constexpr (STATS) {
    __syncthreads();
    float* Sl = Al;  // 2*TY*NC = 2048 floats
#pragma unroll
    for (int j = 0; j < 4; ++j) {
      Sl[ty * NC + c0 + j] = s[j];
      Sl[TY * NC + ty * NC + c0 + j] = q[j];
    }
    __syncthreads();
    if (t < NC) {
      float ss = 0.f, qq = 0.f;
#pragma unroll
      for (int g = 0; g < TY; ++g) {
        ss += Sl[g * NC + t];
        qq += Sl[TY * NC + g * NC + t];
      }
      partials[blockIdx.x * 2 * NC + t] = ss;
      partials[blockIdx.x * 2 * NC + NC + t] = qq;
    }
  }
}

// fold partials across GEMM_NBLK blocks (256 threads, G groups), emit fused
// affine [scale C | shift C]
template <int C>
__global__ void k_finalize(const float* __restrict__ partials, const float* __restrict__ gamma,
                           const float* __restrict__ beta, float* __restrict__ out) {
  constexpr int G = TPB / C;
  __shared__ float lds[2 * TPB];
  int c = threadIdx.x % C, g = threadIdx.x / C;
  float s = 0.f, s2 = 0.f;
  for (int b = g; b < GEMM_NBLK; b += G) {
    s += partials[b * 2 * C + c];
    s2 += partials[b * 2 * C + C + c];
  }
  lds[threadIdx.x] = s;
  lds[TPB + threadIdx.x] = s2;
  __syncthreads();
  if (g == 0) {
#pragma unroll
    for (int k = 1; k < G; ++k) {
      s += lds[k * C + c];
      s2 += lds[TPB + k * C + c];
    }
    float invN = 1.0f / NN;
    float mu = s * invN;
    float var = s2 * invN - mu * mu;
    float rs = rsqrtf(var + BN_EPS) * gamma[c];
    out[c] = rs;
    out[C + c] = beta[c] - mu * rs;
  }
}

// one BLOCK per graph: 4 waves stride the contiguous row range, LDS-reduce.
__global__ void k_poolseg(const float* __restrict__ h, const int* __restrict__ batch,
                          float* __restrict__ g) {
  __shared__ float lds[TPB];
  int gi = blockIdx.x;
  int lane = threadIdx.x & 63, w = threadIdx.x >> 6;
  int a = 0, b = NN;
  while (a < b) { int m = (a + b) >> 1; if (batch[m] < gi) a = m + 1; else b = m; }
  int lo = a;
  b = NN;
  while (a < b) { int m = (a + b) >> 1; if (batch[m] < gi + 1) a = m + 1; else b = m; }
  int hi = a;
  float acc = 0.f;
  for (int n = lo + w; n < hi; n += 4) acc += h[(size_t)n * 64 + lane];
  lds[threadIdx.x] = acc;
  __syncthreads();
  if (w == 0)
    g[gi * 64 + lane] = lds[lane] + lds[64 + lane] + lds[128 + lane] + lds[192 + lane];
}

// out[512,10] = relu(g @ Wh1 + bh1) @ Wh2 + bh2 ; thread per graph
__global__ void k_head(const float* __restrict__ g, const float* __restrict__ Wh1,
                       const float* __restrict__ bh1, const float* __restrict__ Wh2,
                       const float* __restrict__ bh2, float* __restrict__ out) {
  __shared__ float W1l[64 * 32], W2l[32 * 10], b1l[32], b2l[10];
  for (int t = threadIdx.x; t < 64 * 32; t += TPB) W1l[t] = Wh1[t];
  for (int t = threadIdx.x; t < 320; t += TPB) W2l[t] = Wh2[t];
  if (threadIdx.x < 32) b1l[threadIdx.x] = bh1[threadIdx.x];
  if (threadIdx.x < 10) b2l[threadIdx.x] = bh2[threadIdx.x];
  __syncthreads();
  int gi = blockIdx.x * TPB + threadIdx.x;
  if (gi >= NG) return;
  float hid[32];
#pragma unroll
  for (int j = 0; j < 32; ++j) hid[j] = b1l[j];
  for (int k = 0; k < 64; ++k) {
    float gv = g[gi * 64 + k];
#pragma unroll
    for (int j = 0; j < 32; ++j) hid[j] += gv * W1l[k * 32 + j];
  }
  float o[10];
#pragma unroll
  for (int j = 0; j < 10; ++j) o[j] = b2l[j];
#pragma unroll
  for (int k = 0; k < 32; ++k) {
    float hv = fmaxf(hid[k], 0.f);
#pragma unroll
    for (int j = 0; j < 10; ++j) o[j] += hv * W2l[k * 10 + j];
  }
  for (int j = 0; j < 10; ++j) out[gi * 10 + j] = o[j];
}

extern "C" void kernel_launch(void* const* d_in, const int* in_sizes, int n_in,
                              void* d_out, int out_size, void* d_ws, size_t ws_size,
                              hipStream_t stream) {
  const int* x = (const int*)d_in[0];
  const int* ei = (const int*)d_in[1];
  const int* batch = (const int*)d_in[2];
  const float* emb = (const float*)d_in[3];
  const float* W1 = (const float*)d_in[4];
  const float* b1 = (const float*)d_in[5];
  const float* g1 = (const float*)d_in[6];
  const float* bt1 = (const float*)d_in[7];
  const float* W2 = (const float*)d_in[8];
  const float* b2 = (const float*)d_in[9];
  const float* gbn = (const float*)d_in[10];
  const float* bbn = (const float*)d_in[11];
  const float* Wh1 = (const float*)d_in[12];
  const float* bh1 = (const float*)d_in[13];
  const float* Wh2 = (const float*)d_in[14];
  const float* bh2 = (const float*)d_in[15];
  float* out = (float*)d_out;

  const int* e_src = ei;
  const int* e_dst = ei + NE;

  char* ws = (char*)d_ws;
  size_t off = 0;
  auto alloc = [&](size_t bytes) -> void* {
    void* p = ws + off;
    off = (off + bytes + 255) & ~(size_t)255;
    return p;
  };
  float* h = (float*)alloc((size_t)NN * 64 * 4);             // layer-3 output (f32)
  unsigned short* h_bf = (unsigned short*)alloc((size_t)NN * 64 * 2);  // layers 0-2
  float* z2 = (float*)alloc((size_t)NN * 128 * 4);
  int* srcs = (int*)alloc((size_t)NE * 4);
  int* row_ptr = (int*)alloc((size_t)(NN + 1) * 4);
  int* incl = (int*)alloc((size_t)NN * 4);
  int* btot = (int*)alloc(256 * 4);
  float* g = (float*)alloc((size_t)NG * 64 * 4);
  float* partials = (float*)alloc((size_t)GEMM_NBLK * 256 * 4);
  float* statsL = (float*)alloc(4 * 256 * 4);
  float* statsH = (float*)alloc(3 * 128 * 4);
  int* counts = (int*)alloc((size_t)NN * 4);
  int* fill_pos = (int*)alloc((size_t)NN * 4);
  int zero_words = (int)(((char*)fill_pos - (char*)counts) / 4) + NN;

  int gz = (zero_words + TPB - 1) / TPB;
  k_zero<<<gz, TPB, 0, stream>>>(counts, zero_words);

  k_hist<<<EDGE_BLKS, TPB, 0, stream>>>(e_dst, counts);

  int nScanBlocks = (NN + TPB - 1) / TPB;
  k_scan1<<<nScanBlocks, TPB, 0, stream>>>(counts, incl, btot);
  k_scan2<<<1, TPB, 0, stream>>>(btot, nScanBlocks);
  int gScan3 = (NN + 1 + TPB - 1) / TPB;
  k_scan3<<<gScan3, TPB, 0, stream>>>(incl, btot, row_ptr);
  k_fill<<<FILL_P * EDGE_BLKS, TPB, 0, stream>>>(e_src, e_dst, row_ptr, fill_pos, srcs);

  for (int i = 0; i < 4; ++i) {
    const float* W1i = W1 + (size_t)i * 64 * 128;
    const float* b1i = b1 + (size_t)i * 128;
    const float* g1i = g1 + (size_t)i * 128;
    const float* bt1i = bt1 + (size_t)i * 128;
    const float* W2i = W2 + (size_t)i * 128 * 64;
    const float* b2i = b2 + (size_t)i * 64;
    float* stL = statsL + (size_t)i * 256;

    if (i == 0)
      k_agg_gemm1<true><<<GEMM_NBLK, TPB, 0, stream>>>(
          nullptr, x, emb, row_ptr, srcs, nullptr, W1i, b1i, z2, partials);
    else
      k_agg_gemm1<false><<<GEMM_NBLK, TPB, 0, stream>>>(
          h_bf, nullptr, nullptr, row_ptr, srcs, statsH + (size_t)(i - 1) * 128,
          W1i, b1i, z2, partials);

    k_finalize<128><<<1, TPB, 0, stream>>>(partials, g1i, bt1i, stL);

    if (i < 3) {
      float* stH = statsH + (size_t)i * 128;
      k_gemm2<true, true><<<GEMM_NBLK, TPB, 0, stream>>>(z2, W2i, b2i, stL, h_bf, partials);
      k_finalize<64><<<1, TPB, 0, stream>>>(partials, gbn + (size_t)i * 64,
                                            bbn + (size_t)i * 64, stH);
    } else {
      k_gemm2<false, false><<<GEMM_NBLK, TPB, 0, stream>>>(z2, W2i, b2i, stL, h, partials);
    }
  }

  k_poolseg<<<NG, TPB, 0, stream>>>(h, batch, g);
  k_head<<<(NG + TPB - 1) / TPB, TPB, 0, stream>>>(g, Wh1, bh1, Wh2, bh2, out);
}

// Round 7
// 970.201 us; speedup vs baseline: 1.2377x; 1.2377x over previous
//
#include <hip/hip_runtime.h>

#define NN 50000
#define NE 800000
#define NG 512
#define TPB 256
#define BN_EPS 1e-5f
#define GEMM_NBLK 782   // ceil(NN/64)
#define EDGE_BLKS 3125  // NE/TPB exactly
#define FILL_P 8
#define FILL_CHUNK 6250  // NN/FILL_P

__device__ __forceinline__ float bf2f(unsigned short u) {
  return __uint_as_float(((unsigned)u) << 16);
}
__device__ __forceinline__ unsigned short f2bf(float f) {
  unsigned u = __float_as_uint(f);
  u += 0x7FFFu + ((u >> 16) & 1u);  // round-to-nearest-even
  return (unsigned short)(u >> 16);
}

__global__ void k_zero(int* __restrict__ p, int n) {
  int i = blockIdx.x * TPB + threadIdx.x;
  if (i < n) p[i] = 0;
}

__global__ void k_hist(const int* __restrict__ dst, int* __restrict__ counts) {
  int e = blockIdx.x * TPB + threadIdx.x;
  if (e < NE) atomicAdd(&counts[dst[e]], 1);
}

__global__ void k_scan1(const int* __restrict__ counts, int* __restrict__ incl,
                        int* __restrict__ btot) {
  __shared__ int lds[TPB];
  int i = blockIdx.x * TPB + threadIdx.x;
  int v = (i < NN) ? counts[i] : 0;
  lds[threadIdx.x] = v;
  __syncthreads();
  for (int off = 1; off < TPB; off <<= 1) {
    int t = (threadIdx.x >= off) ? lds[threadIdx.x - off] : 0;
    __syncthreads();
    lds[threadIdx.x] += t;
    __syncthreads();
  }
  if (i < NN) incl[i] = lds[threadIdx.x];
  if (threadIdx.x == TPB - 1) btot[blockIdx.x] = lds[TPB - 1];
}

__global__ void k_scan2(int* __restrict__ btot, int nb) {
  __shared__ int lds[TPB];
  int t = (threadIdx.x < nb) ? btot[threadIdx.x] : 0;
  int own = t;
  lds[threadIdx.x] = t;
  __syncthreads();
  for (int off = 1; off < TPB; off <<= 1) {
    int u = (threadIdx.x >= off) ? lds[threadIdx.x - off] : 0;
    __syncthreads();
    lds[threadIdx.x] += u;
    __syncthreads();
  }
  btot[threadIdx.x] = lds[threadIdx.x] - own;
}

__global__ void k_scan3(const int* __restrict__ incl, const int* __restrict__ btot,
                        int* __restrict__ row_ptr) {
  int i = blockIdx.x * TPB + threadIdx.x;
  if (i == 0) row_ptr[0] = 0;
  if (i < NN) row_ptr[i + 1] = incl[i] + btot[i >> 8];
}

// counting-sort fill (one-time CSR build)
__global__ void k_fill(const int* __restrict__ src, const int* __restrict__ dst,
                       const int* __restrict__ row_ptr, int* __restrict__ fill_pos,
                       int* __restrict__ srcs) {
  int pass = blockIdx.x & 7;
  int e = (blockIdx.x >> 3) * TPB + threadIdx.x;
  int d = dst[e];
  if (d / FILL_CHUNK != pass) return;
  int pos = row_ptr[d] + atomicAdd(&fill_pos[d], 1);
  srcs[pos] = src[e];
}

// Layer-0 aggregate: h implicit = emb[x[n]] (emb 8KB -> L1-hot). Wave per node.
__global__ void k_aggregate0(const int* __restrict__ x, const float* __restrict__ emb,
                             const int* __restrict__ row_ptr, const int* __restrict__ srcs,
                             float* __restrict__ z) {
  int wid = (blockIdx.x * TPB + threadIdx.x) >> 6;
  int lane = threadIdx.x & 63;
  if (wid >= NN) return;
  int beg = row_ptr[wid], end = row_ptr[wid + 1];
  float acc = emb[x[wid] * 64 + lane];
  int e = beg;
  for (; e + 4 <= end; e += 4) {
    int x0 = x[srcs[e]], x1 = x[srcs[e + 1]], x2 = x[srcs[e + 2]], x3 = x[srcs[e + 3]];
    acc += emb[x0 * 64 + lane] + emb[x1 * 64 + lane] + emb[x2 * 64 + lane] +
           emb[x3 * 64 + lane];
  }
  for (; e < end; ++e) acc += emb[x[srcs[e]] * 64 + lane];
  z[wid * 64 + lane] = acc;
}

// Layers 1..3 aggregate over bf16 h, BN affine of prev layer folded in:
//   z = sc*(h_self + sum h_src) + (1+deg)*sh
// Wave per node; per-lane 4B loads (uint = 2 bf16 features, 32 lanes/row):
// lanes 0-31 take even edges, lanes 32-63 odd edges; one shfl_xor(32) combines.
__global__ void k_aggregate_bf(const unsigned short* __restrict__ h_bf,
                               const int* __restrict__ row_ptr,
                               const int* __restrict__ srcs,
                               const float* __restrict__ bnst,
                               float* __restrict__ z) {
  int wid = (blockIdx.x * TPB + threadIdx.x) >> 6;
  int lane = threadIdx.x & 63;
  if (wid >= NN) return;
  int half = lane >> 5, l = lane & 31;
  int beg = row_ptr[wid], end = row_ptr[wid + 1];
  float a0 = 0.f, a1 = 0.f;
  if (half == 0) {
    unsigned u = *(const unsigned*)&h_bf[(size_t)wid * 64 + 2 * l];
    a0 = bf2f((unsigned short)u);
    a1 = bf2f((unsigned short)(u >> 16));
  }
  int e = beg + half;
  for (; e + 6 < end; e += 8) {  // 4 rows in flight per half-wave
    int s0 = srcs[e], s1 = srcs[e + 2], s2 = srcs[e + 4], s3 = srcs[e + 6];
    unsigned u0 = *(const unsigned*)&h_bf[(size_t)s0 * 64 + 2 * l];
    unsigned u1 = *(const unsigned*)&h_bf[(size_t)s1 * 64 + 2 * l];
    unsigned u2 = *(const unsigned*)&h_bf[(size_t)s2 * 64 + 2 * l];
    unsigned u3 = *(const unsigned*)&h_bf[(size_t)s3 * 64 + 2 * l];
    a0 += (bf2f((unsigned short)u0) + bf2f((unsigned short)u1)) +
          (bf2f((unsigned short)u2) + bf2f((unsigned short)u3));
    a1 += (bf2f((unsigned short)(u0 >> 16)) + bf2f((unsigned short)(u1 >> 16))) +
          (bf2f((unsigned short)(u2 >> 16)) + bf2f((unsigned short)(u3 >> 16)));
  }
  for (; e < end; e += 2) {
    unsigned u = *(const unsigned*)&h_bf[(size_t)srcs[e] * 64 + 2 * l];
    a0 += bf2f((unsigned short)u);
    a1 += bf2f((unsigned short)(u >> 16));
  }
  a0 += __shfl_xor(a0, 32);
  a1 += __shfl_xor(a1, 32);
  if (half == 0) {
    float2 scv = *(const float2*)&bnst[2 * l];
    float2 shv = *(const float2*)&bnst[64 + 2 * l];
    float d1 = (float)(1 + end - beg);
    *(float2*)&z[(size_t)wid * 64 + 2 * l] =
        make_float2(fmaf(scv.x, a0, d1 * shv.x), fmaf(scv.y, a1, d1 * shv.y));
  }
}

// GEMM1: z2[N,128] = z[N,64] @ W[64,128] + b1, with per-block column stats.
__global__ __launch_bounds__(TPB) void k_gemm1(const float* __restrict__ in,
                                               const float* __restrict__ W,
                                               const float* __restrict__ bias,
                                               float* __restrict__ z2,
                                               float* __restrict__ partials) {
  constexpr int K = 64, NC = 128, LDA = 68;
  constexpr int TX = 32, TY = 8, RT = 8;
  __shared__ float Al[64 * LDA];
  __shared__ float Wl[K * NC];
  const int t = threadIdx.x;
  const int r0 = blockIdx.x * 64;

  {
    const float4* Wg = (const float4*)W;
    float4* Wl4 = (float4*)Wl;
#pragma unroll
    for (int j = 0; j < (K * NC / 4) / TPB; ++j) Wl4[t + j * TPB] = Wg[t + j * TPB];
  }
#pragma unroll
  for (int j = 0; j < 4; ++j) {
    int qi = t + j * TPB;
    int row = qi >> 4, cq = qi & 15;
    int r = r0 + row;
    float4 v = make_float4(0.f, 0.f, 0.f, 0.f);
    if (r < NN) v = *(const float4*)&in[(size_t)r * 64 + cq * 4];
    *(float4*)&Al[row * LDA + cq * 4] = v;
  }
  __syncthreads();

  const int tx = t % TX, ty = t / TX;
  const int c0 = tx * 4;
  float4 b0 = *(const float4*)&bias[c0];
  float acc[RT][4];
#pragma unroll
  for (int i = 0; i < RT; ++i) {
    acc[i][0] = b0.x; acc[i][1] = b0.y; acc[i][2] = b0.z; acc[i][3] = b0.w;
  }
  const float* Ab = &Al[ty * RT * LDA];
#pragma unroll 4
  for (int k4 = 0; k4 < K / 4; ++k4) {
    float4 a[RT];
#pragma unroll
    for (int i = 0; i < RT; ++i) a[i] = *(const float4*)&Ab[i * LDA + k4 * 4];
#pragma unroll
    for (int kk = 0; kk < 4; ++kk) {
      float4 b = *(const float4*)&Wl[(k4 * 4 + kk) * NC + c0];
#pragma unroll
      for (int i = 0; i < RT; ++i) {
        float av = (&a[i].x)[kk];
        acc[i][0] = fmaf(av, b.x, acc[i][0]);
        acc[i][1] = fmaf(av, b.y, acc[i][1]);
        acc[i][2] = fmaf(av, b.z, acc[i][2]);
        acc[i][3] = fmaf(av, b.w, acc[i][3]);
      }
    }
  }
  float s[4] = {0.f, 0.f, 0.f, 0.f}, q[4] = {0.f, 0.f, 0.f, 0.f};
#pragma unroll
  for (int i = 0; i < RT; ++i) {
    int r = r0 + ty * RT + i;
    if (r < NN) {
      *(float4*)&z2[(size_t)r * NC + c0] =
          make_float4(acc[i][0], acc[i][1], acc[i][2], acc[i][3]);
      s[0] += acc[i][0]; q[0] += acc[i][0] * acc[i][0];
      s[1] += acc[i][1]; q[1] += acc[i][1] * acc[i][1];
      s[2] += acc[i][2]; q[2] += acc[i][2] * acc[i][2];
      s[3] += acc[i][3]; q[3] += acc[i][3] * acc[i][3];
    }
  }
  __syncthreads();
  float* Sl = Al;  // 2*TY*NC = 2048 floats
#pragma unroll
  for (int j = 0; j < 4; ++j) {
    Sl[ty * NC + c0 + j] = s[j];
    Sl[TY * NC + ty * NC + c0 + j] = q[j];
  }
  __syncthreads();
  if (t < NC) {
    float ss = 0.f, qq = 0.f;
#pragma unroll
    for (int g = 0; g < TY; ++g) {
      ss += Sl[g * NC + t];
      qq += Sl[TY * NC + g * NC + t];
    }
    partials[blockIdx.x * 2 * NC + t] = ss;
    partials[blockIdx.x * 2 * NC + NC + t] = qq;
  }
}

// GEMM2: h[N,64] = relu( relu(bn1(z2)) @ W[128,64] + b2 )
// OUT_BF16: store h as bf16 (next layer's gather source); stats from f32.
template <bool STATS, bool OUT_BF16>
__global__ __launch_bounds__(TPB) void k_gemm2(const float* __restrict__ in,
                                               const float* __restrict__ W,
                                               const float* __restrict__ bias,
                                               const float* __restrict__ bnst,
                                               void* __restrict__ outp,
                                               float* __restrict__ partials) {
  constexpr int K = 128, NC = 64, LDA = 128;
  constexpr int TX = 16, TY = 16, RT = 4;
  __shared__ float Al[64 * LDA];
  __shared__ float Wl[K * NC];
  const int t = threadIdx.x;
  const int r0 = blockIdx.x * 64;

  {
    const float4* Wg = (const float4*)W;
    float4* Wl4 = (float4*)Wl;
#pragma unroll
    for (int j = 0; j < (K * NC / 4) / TPB; ++j) Wl4[t + j * TPB] = Wg[t + j * TPB];
  }
  {
    int cq = t & 31, rb = t >> 5;
    float4 sc4 = *(const float4*)&bnst[cq * 4];
    float4 sh4 = *(const float4*)&bnst[K + cq * 4];
#pragma unroll
    for (int j = 0; j < 8; ++j) {
      int row = rb + j * 8;
      int r = r0 + row;
      float4 v = make_float4(0.f, 0.f, 0.f, 0.f);
      if (r < NN) {
        v = *(const float4*)&in[(size_t)r * 128 + cq * 4];
        v.x = fmaxf(fmaf(v.x, sc4.x, sh4.x), 0.f);
        v.y = fmaxf(fmaf(v.y, sc4.y, sh4.y), 0.f);
        v.z = fmaxf(fmaf(v.z, sc4.z, sh4.z), 0.f);
        v.w = fmaxf(fmaf(v.w, sc4.w, sh4.w), 0.f);
      }
      *(float4*)&Al[row * LDA + cq * 4] = v;
    }
  }
  __syncthreads();

  const int tx = t % TX, ty = t / TX;
  const int c0 = tx * 4;
  float4 b0 = *(const float4*)&bias[c0];
  float acc[RT][4];
#pragma unroll
  for (int i = 0; i < RT; ++i) {
    acc[i][0] = b0.x; acc[i][1] = b0.y; acc[i][2] = b0.z; acc[i][3] = b0.w;
  }
  const float* Ab = &Al[ty * RT * LDA];
#pragma unroll 4
  for (int k4 = 0; k4 < K / 4; ++k4) {
    float4 a[RT];
#pragma unroll
    for (int i = 0; i < RT; ++i) a[i] = *(const float4*)&Ab[i * LDA + k4 * 4];
#pragma unroll
    for (int kk = 0; kk < 4; ++kk) {
      float4 b = *(const float4*)&Wl[(k4 * 4 + kk) * NC + c0];
#pragma unroll
      for (int i = 0; i < RT; ++i) {
        float av = (&a[i].x)[kk];
        acc[i][0] = fmaf(av, b.x, acc[i][0]);
        acc[i][1] = fmaf(av, b.y, acc[i][1]);
        acc[i][2] = fmaf(av, b.z, acc[i][2]);
        acc[i][3] = fmaf(av, b.w, acc[i][3]);
      }
    }
  }
  float s[4] = {0.f, 0.f, 0.f, 0.f}, q[4] = {0.f, 0.f, 0.f, 0.f};
#pragma unroll
  for (int i = 0; i < RT; ++i) {
    int r = r0 + ty * RT + i;
    if (r < NN) {
      float ox = fmaxf(acc[i][0], 0.f), oy = fmaxf(acc[i][1], 0.f);
      float oz = fmaxf(acc[i][2], 0.f), ow = fmaxf(acc[i][3], 0.f);
      if constexpr (OUT_BF16) {
        ushort4 o = make_ushort4(f2bf(ox), f2bf(oy), f2bf(oz), f2bf(ow));
        *(ushort4*)&((unsigned short*)outp)[(size_t)r * NC + c0] = o;
      } else {
        *(float4*)&((float*)outp)[(size_t)r * NC + c0] = make_float4(ox, oy, oz, ow);
      }
      if constexpr (STATS) {
        s[0] += ox; q[0] += ox * ox;
        s[1] += oy; q[1] += oy * oy;
        s[2] += oz; q[2] += oz * oz;
        s[3] += ow; q[3] += ow * ow;
      }
    }
  }
  if constexpr (STATS) {
    __syncthreads();
    float* Sl = Al;
#pragma unroll
    for (int j = 0; j < 4; ++j) {
      Sl[ty * NC + c0 + j] = s[j];
      Sl[TY * NC + ty * NC + c0 + j] = q[j];
    }
    __syncthreads();
    if (t < NC) {
      float ss = 0.f, qq = 0.f;
#pragma unroll
      for (int g = 0; g < TY; ++g) {
        ss += Sl[g * NC + t];
        qq += Sl[TY * NC + g * NC + t];
      }
      partials[blockIdx.x * 2 * NC + t] = ss;
      partials[blockIdx.x * 2 * NC + NC + t] = qq;
    }
  }
}

// fold partials across GEMM_NBLK blocks (256 threads), emit [scale C | shift C]
template <int C>
__global__ void k_finalize(const float* __restrict__ partials, const float* __restrict__ gamma,
                           const float* __restrict__ beta, float* __restrict__ out) {
  constexpr int G = TPB / C;
  __shared__ float lds[2 * TPB];
  int c = threadIdx.x % C, g = threadIdx.x / C;
  float s = 0.f, s2 = 0.f;
  for (int b = g; b < GEMM_NBLK; b += G) {
    s += partials[b * 2 * C + c];
    s2 += partials[b * 2 * C + C + c];
  }
  lds[threadIdx.x] = s;
  lds[TPB + threadIdx.x] = s2;
  __syncthreads();
  if (g == 0) {
#pragma unroll
    for (int k = 1; k < G; ++k) {
      s += lds[k * C + c];
      s2 += lds[TPB + k * C + c];
    }
    float invN = 1.0f / NN;
    float mu = s * invN;
    float var = s2 * invN - mu * mu;
    float rs = rsqrtf(var + BN_EPS) * gamma[c];
    out[c] = rs;
    out[C + c] = beta[c] - mu * rs;
  }
}

// one BLOCK per graph: 4 waves stride the contiguous row range, LDS-reduce.
__global__ void k_poolseg(const float* __restrict__ h, const int* __restrict__ batch,
                          float* __restrict__ g) {
  __shared__ float lds[TPB];
  int gi = blockIdx.x;
  int lane = threadIdx.x & 63, w = threadIdx.x >> 6;
  int a = 0, b = NN;
  while (a < b) { int m = (a + b) >> 1; if (batch[m] < gi) a = m + 1; else b = m; }
  int lo = a;
  b = NN;
  while (a < b) { int m = (a + b) >> 1; if (batch[m] < gi + 1) a = m + 1; else b = m; }
  int hi = a;
  float acc = 0.f;
  for (int n = lo + w; n < hi; n += 4) acc += h[(size_t)n * 64 + lane];
  lds[threadIdx.x] = acc;
  __syncthreads();
  if (w == 0)
    g[gi * 64 + lane] = lds[lane] + lds[64 + lane] + lds[128 + lane] + lds[192 + lane];
}

// out[512,10] = relu(g @ Wh1 + bh1) @ Wh2 + bh2 ; thread per graph
__global__ void k_head(const float* __restrict__ g, const float* __restrict__ Wh1,
                       const float* __restrict__ bh1, const float* __restrict__ Wh2,
                       const float* __restrict__ bh2, float* __restrict__ out) {
  __shared__ float W1l[64 * 32], W2l[32 * 10], b1l[32], b2l[10];
  for (int t = threadIdx.x; t < 64 * 32; t += TPB) W1l[t] = Wh1[t];
  for (int t = threadIdx.x; t < 320; t += TPB) W2l[t] = Wh2[t];
  if (threadIdx.x < 32) b1l[threadIdx.x] = bh1[threadIdx.x];
  if (threadIdx.x < 10) b2l[threadIdx.x] = bh2[threadIdx.x];
  __syncthreads();
  int gi = blockIdx.x * TPB + threadIdx.x;
  if (gi >= NG) return;
  float hid[32];
#pragma unroll
  for (int j = 0; j < 32; ++j) hid[j] = b1l[j];
  for (int k = 0; k < 64; ++k) {
    float gv = g[gi * 64 + k];
#pragma unroll
    for (int j = 0; j < 32; ++j) hid[j] += gv * W1l[k * 32 + j];
  }
  float o[10];
#pragma unroll
  for (int j = 0; j < 10; ++j) o[j] = b2l[j];
#pragma unroll
  for (int k = 0; k < 32; ++k) {
    float hv = fmaxf(hid[k], 0.f);
#pragma unroll
    for (int j = 0; j < 10; ++j) o[j] += hv * W2l[k * 10 + j];
  }
  for (int j = 0; j < 10; ++j) out[gi * 10 + j] = o[j];
}

extern "C" void kernel_launch(void* const* d_in, const int* in_sizes, int n_in,
                              void* d_out, int out_size, void* d_ws, size_t ws_size,
                              hipStream_t stream) {
  const int* x = (const int*)d_in[0];
  const int* ei = (const int*)d_in[1];
  const int* batch = (const int*)d_in[2];
  const float* emb = (const float*)d_in[3];
  const float* W1 = (const float*)d_in[4];
  const float* b1 = (const float*)d_in[5];
  const float* g1 = (const float*)d_in[6];
  const float* bt1 = (const float*)d_in[7];
  const float* W2 = (const float*)d_in[8];
  const float* b2 = (const float*)d_in[9];
  const float* gbn = (const float*)d_in[10];
  const float* bbn = (const float*)d_in[11];
  const float* Wh1 = (const float*)d_in[12];
  const float* bh1 = (const float*)d_in[13];
  const float* Wh2 = (const float*)d_in[14];
  const float* bh2 = (const float*)d_in[15];
  float* out = (float*)d_out;

  const int* e_src = ei;
  const int* e_dst = ei + NE;

  char* ws = (char*)d_ws;
  size_t off = 0;
  auto alloc = [&](size_t bytes) -> void* {
    void* p = ws + off;
    off = (off + bytes + 255) & ~(size_t)255;
    return p;
  };
  float* h = (float*)alloc((size_t)NN * 64 * 4);  // layer-3 output (f32)
  unsigned short* h_bf = (unsigned short*)alloc((size_t)NN * 64 * 2);  // layers 0-2
  float* z = (float*)alloc((size_t)NN * 64 * 4);
  float* z2 = (float*)alloc((size_t)NN * 128 * 4);
  int* srcs = (int*)alloc((size_t)NE * 4);
  int* row_ptr = (int*)alloc((size_t)(NN + 1) * 4);
  int* incl = (int*)alloc((size_t)NN * 4);
  int* btot = (int*)alloc(256 * 4);
  float* g = (float*)alloc((size_t)NG * 64 * 4);
  float* partials = (float*)alloc((size_t)GEMM_NBLK * 256 * 4);
  float* statsL = (float*)alloc(4 * 256 * 4);
  float* statsH = (float*)alloc(3 * 128 * 4);
  int* counts = (int*)alloc((size_t)NN * 4);
  int* fill_pos = (int*)alloc((size_t)NN * 4);
  int zero_words = (int)(((char*)fill_pos - (char*)counts) / 4) + NN;

  int gz = (zero_words + TPB - 1) / TPB;
  k_zero<<<gz, TPB, 0, stream>>>(counts, zero_words);

  k_hist<<<EDGE_BLKS, TPB, 0, stream>>>(e_dst, counts);

  int nScanBlocks = (NN + TPB - 1) / TPB;
  k_scan1<<<nScanBlocks, TPB, 0, stream>>>(counts, incl, btot);
  k_scan2<<<1, TPB, 0, stream>>>(btot, nScanBlocks);
  int gScan3 = (NN + 1 + TPB - 1) / TPB;
  k_scan3<<<gScan3, TPB, 0, stream>>>(incl, btot, row_ptr);
  k_fill<<<FILL_P * EDGE_BLKS, TPB, 0, stream>>>(e_src, e_dst, row_ptr, fill_pos, srcs);

  int gAgg = (NN * 64 + TPB - 1) / TPB;  // 12500 (wave per node)

  for (int i = 0; i < 4; ++i) {
    const float* W1i = W1 + (size_t)i * 64 * 128;
    const float* b1i = b1 + (size_t)i * 128;
    const float* g1i = g1 + (size_t)i * 128;
    const float* bt1i = bt1 + (size_t)i * 128;
    const float* W2i = W2 + (size_t)i * 128 * 64;
    const float* b2i = b2 + (size_t)i * 64;
    float* stL = statsL + (size_t)i * 256;

    if (i == 0)
      k_aggregate0<<<gAgg, TPB, 0, stream>>>(x, emb, row_ptr, srcs, z);
    else
      k_aggregate_bf<<<gAgg, TPB, 0, stream>>>(h_bf, row_ptr, srcs,
                                               statsH + (size_t)(i - 1) * 128, z);

    k_gemm1<<<GEMM_NBLK, TPB, 0, stream>>>(z, W1i, b1i, z2, partials);
    k_finalize<128><<<1, TPB, 0, stream>>>(partials, g1i, bt1i, stL);

    if (i < 3) {
      float* stH = statsH + (size_t)i * 128;
      k_gemm2<true, true><<<GEMM_NBLK, TPB, 0, stream>>>(z2, W2i, b2i, stL, h_bf, partials);
      k_finalize<64><<<1, TPB, 0, stream>>>(partials, gbn + (size_t)i * 64,
                                            bbn + (size_t)i * 64, stH);
    } else {
      k_gemm2<false, false><<<GEMM_NBLK, TPB, 0, stream>>>(z2, W2i, b2i, stL, h, partials);
    }
  }

  k_poolseg<<<NG, TPB, 0, stream>>>(h, batch, g);
  k_head<<<(NG + TPB - 1) / TPB, TPB, 0, stream>>>(g, Wh1, bh1, Wh2, bh2, out);
}

// Round 8
// 512.001 us; speedup vs baseline: 2.3453x; 1.8949x over previous
//
#include <hip/hip_runtime.h>

#define NN 50000
#define NE 800000
#define NG 512
#define TPB 256
#define BN_EPS 1e-5f
#define NBLK_G 784      // GEMM grid: ceil(NN/64)=782, padded to 784 (=16*49) so
                        // finalize's per-group trip count is a compile-time const
#define EDGE_BLKS 3125  // NE/TPB exactly
#define FILL_P 8
#define FILL_CHUNK 6250  // NN/FILL_P
#define TPB_FIN 512

__device__ __forceinline__ float bf2f(unsigned short u) {
  return __uint_as_float(((unsigned)u) << 16);
}
__device__ __forceinline__ unsigned short f2bf(float f) {
  unsigned u = __float_as_uint(f);
  u += 0x7FFFu + ((u >> 16) & 1u);  // round-to-nearest-even
  return (unsigned short)(u >> 16);
}

__global__ void k_zero(int* __restrict__ p, int n) {
  int i = blockIdx.x * TPB + threadIdx.x;
  if (i < n) p[i] = 0;
}

__global__ void k_hist(const int* __restrict__ dst, int* __restrict__ counts) {
  int e = blockIdx.x * TPB + threadIdx.x;
  if (e < NE) atomicAdd(&counts[dst[e]], 1);
}

__global__ void k_scan1(const int* __restrict__ counts, int* __restrict__ incl,
                        int* __restrict__ btot) {
  __shared__ int lds[TPB];
  int i = blockIdx.x * TPB + threadIdx.x;
  int v = (i < NN) ? counts[i] : 0;
  lds[threadIdx.x] = v;
  __syncthreads();
  for (int off = 1; off < TPB; off <<= 1) {
    int t = (threadIdx.x >= off) ? lds[threadIdx.x - off] : 0;
    __syncthreads();
    lds[threadIdx.x] += t;
    __syncthreads();
  }
  if (i < NN) incl[i] = lds[threadIdx.x];
  if (threadIdx.x == TPB - 1) btot[blockIdx.x] = lds[TPB - 1];
}

__global__ void k_scan2(int* __restrict__ btot, int nb) {
  __shared__ int lds[TPB];
  int t = (threadIdx.x < nb) ? btot[threadIdx.x] : 0;
  int own = t;
  lds[threadIdx.x] = t;
  __syncthreads();
  for (int off = 1; off < TPB; off <<= 1) {
    int u = (threadIdx.x >= off) ? lds[threadIdx.x - off] : 0;
    __syncthreads();
    lds[threadIdx.x] += u;
    __syncthreads();
  }
  btot[threadIdx.x] = lds[threadIdx.x] - own;
}

__global__ void k_scan3(const int* __restrict__ incl, const int* __restrict__ btot,
                        int* __restrict__ row_ptr) {
  int i = blockIdx.x * TPB + threadIdx.x;
  if (i == 0) row_ptr[0] = 0;
  if (i < NN) row_ptr[i + 1] = incl[i] + btot[i >> 8];
}

// counting-sort fill (one-time CSR build)
__global__ void k_fill(const int* __restrict__ src, const int* __restrict__ dst,
                       const int* __restrict__ row_ptr, int* __restrict__ fill_pos,
                       int* __restrict__ srcs) {
  int pass = blockIdx.x & 7;
  int e = (blockIdx.x >> 3) * TPB + threadIdx.x;
  int d = dst[e];
  if (d / FILL_CHUNK != pass) return;
  int pos = row_ptr[d] + atomicAdd(&fill_pos[d], 1);
  srcs[pos] = src[e];
}

// Layer-0 aggregate: h implicit = emb[x[n]] (emb 8KB -> L1-hot). Wave per node.
__global__ void k_aggregate0(const int* __restrict__ x, const float* __restrict__ emb,
                             const int* __restrict__ row_ptr, const int* __restrict__ srcs,
                             float* __restrict__ z) {
  int wid = (blockIdx.x * TPB + threadIdx.x) >> 6;
  int lane = threadIdx.x & 63;
  if (wid >= NN) return;
  int beg = row_ptr[wid], end = row_ptr[wid + 1];
  float acc = emb[x[wid] * 64 + lane];
  int e = beg;
  for (; e + 4 <= end; e += 4) {
    int x0 = x[srcs[e]], x1 = x[srcs[e + 1]], x2 = x[srcs[e + 2]], x3 = x[srcs[e + 3]];
    acc += emb[x0 * 64 + lane] + emb[x1 * 64 + lane] + emb[x2 * 64 + lane] +
           emb[x3 * 64 + lane];
  }
  for (; e < end; ++e) acc += emb[x[srcs[e]] * 64 + lane];
  z[wid * 64 + lane] = acc;
}

// Layers 1..3 aggregate over bf16 h, BN affine of prev layer folded in:
//   z = sc*(h_self + sum h_src) + (1+deg)*sh
// Wave per node; per-lane 4B loads (uint = 2 bf16, 32 lanes/row); halves split
// even/odd edges, one shfl_xor(32) combines.
__global__ void k_aggregate_bf(const unsigned short* __restrict__ h_bf,
                               const int* __restrict__ row_ptr,
                               const int* __restrict__ srcs,
                               const float* __restrict__ bnst,
                               float* __restrict__ z) {
  int wid = (blockIdx.x * TPB + threadIdx.x) >> 6;
  int lane = threadIdx.x & 63;
  if (wid >= NN) return;
  int half = lane >> 5, l = lane & 31;
  int beg = row_ptr[wid], end = row_ptr[wid + 1];
  float a0 = 0.f, a1 = 0.f;
  if (half == 0) {
    unsigned u = *(const unsigned*)&h_bf[(size_t)wid * 64 + 2 * l];
    a0 = bf2f((unsigned short)u);
    a1 = bf2f((unsigned short)(u >> 16));
  }
  int e = beg + half;
  for (; e + 6 < end; e += 8) {
    int s0 = srcs[e], s1 = srcs[e + 2], s2 = srcs[e + 4], s3 = srcs[e + 6];
    unsigned u0 = *(const unsigned*)&h_bf[(size_t)s0 * 64 + 2 * l];
    unsigned u1 = *(const unsigned*)&h_bf[(size_t)s1 * 64 + 2 * l];
    unsigned u2 = *(const unsigned*)&h_bf[(size_t)s2 * 64 + 2 * l];
    unsigned u3 = *(const unsigned*)&h_bf[(size_t)s3 * 64 + 2 * l];
    a0 += (bf2f((unsigned short)u0) + bf2f((unsigned short)u1)) +
          (bf2f((unsigned short)u2) + bf2f((unsigned short)u3));
    a1 += (bf2f((unsigned short)(u0 >> 16)) + bf2f((unsigned short)(u1 >> 16))) +
          (bf2f((unsigned short)(u2 >> 16)) + bf2f((unsigned short)(u3 >> 16)));
  }
  for (; e < end; e += 2) {
    unsigned u = *(const unsigned*)&h_bf[(size_t)srcs[e] * 64 + 2 * l];
    a0 += bf2f((unsigned short)u);
    a1 += bf2f((unsigned short)(u >> 16));
  }
  a0 += __shfl_xor(a0, 32);
  a1 += __shfl_xor(a1, 32);
  if (half == 0) {
    float2 scv = *(const float2*)&bnst[2 * l];
    float2 shv = *(const float2*)&bnst[64 + 2 * l];
    float d1 = (float)(1 + end - beg);
    *(float2*)&z[(size_t)wid * 64 + 2 * l] =
        make_float2(fmaf(scv.x, a0, d1 * shv.x), fmaf(scv.y, a1, d1 * shv.y));
  }
}

// GEMM1: z2[N,128] = z[N,64] @ W[64,128] + b1, with per-block column stats.
__global__ __launch_bounds__(TPB) void k_gemm1(const float* __restrict__ in,
                                               const float* __restrict__ W,
                                               const float* __restrict__ bias,
                                               float* __restrict__ z2,
                                               float* __restrict__ partials) {
  constexpr int K = 64, NC = 128, LDA = 68;
  constexpr int TX = 32, TY = 8, RT = 8;
  __shared__ float Al[64 * LDA];
  __shared__ float Wl[K * NC];
  const int t = threadIdx.x;
  const int r0 = blockIdx.x * 64;

  {
    const float4* Wg = (const float4*)W;
    float4* Wl4 = (float4*)Wl;
#pragma unroll
    for (int j = 0; j < (K * NC / 4) / TPB; ++j) Wl4[t + j * TPB] = Wg[t + j * TPB];
  }
#pragma unroll
  for (int j = 0; j < 4; ++j) {
    int qi = t + j * TPB;
    int row = qi >> 4, cq = qi & 15;
    int r = r0 + row;
    float4 v = make_float4(0.f, 0.f, 0.f, 0.f);
    if (r < NN) v = *(const float4*)&in[(size_t)r * 64 + cq * 4];
    *(float4*)&Al[row * LDA + cq * 4] = v;
  }
  __syncthreads();

  const int tx = t % TX, ty = t / TX;
  const int c0 = tx * 4;
  float4 b0 = *(const float4*)&bias[c0];
  float acc[RT][4];
#pragma unroll
  for (int i = 0; i < RT; ++i) {
    acc[i][0] = b0.x; acc[i][1] = b0.y; acc[i][2] = b0.z; acc[i][3] = b0.w;
  }
  const float* Ab = &Al[ty * RT * LDA];
#pragma unroll 4
  for (int k4 = 0; k4 < K / 4; ++k4) {
    float4 a[RT];
#pragma unroll
    for (int i = 0; i < RT; ++i) a[i] = *(const float4*)&Ab[i * LDA + k4 * 4];
#pragma unroll
    for (int kk = 0; kk < 4; ++kk) {
      float4 b = *(const float4*)&Wl[(k4 * 4 + kk) * NC + c0];
#pragma unroll
      for (int i = 0; i < RT; ++i) {
        float av = (&a[i].x)[kk];
        acc[i][0] = fmaf(av, b.x, acc[i][0]);
        acc[i][1] = fmaf(av, b.y, acc[i][1]);
        acc[i][2] = fmaf(av, b.z, acc[i][2]);
        acc[i][3] = fmaf(av, b.w, acc[i][3]);
      }
    }
  }
  float s[4] = {0.f, 0.f, 0.f, 0.f}, q[4] = {0.f, 0.f, 0.f, 0.f};
#pragma unroll
  for (int i = 0; i < RT; ++i) {
    int r = r0 + ty * RT + i;
    if (r < NN) {
      *(float4*)&z2[(size_t)r * NC + c0] =
          make_float4(acc[i][0], acc[i][1], acc[i][2], acc[i][3]);
      s[0] += acc[i][0]; q[0] += acc[i][0] * acc[i][0];
      s[1] += acc[i][1]; q[1] += acc[i][1] * acc[i][1];
      s[2] += acc[i][2]; q[2] += acc[i][2] * acc[i][2];
      s[3] += acc[i][3]; q[3] += acc[i][3] * acc[i][3];
    }
  }
  __syncthreads();
  float* Sl = Al;  // 2*TY*NC = 2048 floats
#pragma unroll
  for (int j = 0; j < 4; ++j) {
    Sl[ty * NC + c0 + j] = s[j];
    Sl[TY * NC + ty * NC + c0 + j] = q[j];
  }
  __syncthreads();
  if (t < NC) {
    float ss = 0.f, qq = 0.f;
#pragma unroll
    for (int g = 0; g < TY; ++g) {
      ss += Sl[g * NC + t];
      qq += Sl[TY * NC + g * NC + t];
    }
    partials[blockIdx.x * 2 * NC + t] = ss;
    partials[blockIdx.x * 2 * NC + NC + t] = qq;
  }
}

// GEMM2: h[N,64] = relu( relu(bn1(z2)) @ W[128,64] + b2 )
template <bool STATS, bool OUT_BF16>
__global__ __launch_bounds__(TPB) void k_gemm2(const float* __restrict__ in,
                                               const float* __restrict__ W,
                                               const float* __restrict__ bias,
                                               const float* __restrict__ bnst,
                                               void* __restrict__ outp,
                                               float* __restrict__ partials) {
  constexpr int K = 128, NC = 64, LDA = 128;
  constexpr int TX = 16, TY = 16, RT = 4;
  __shared__ float Al[64 * LDA];
  __shared__ float Wl[K * NC];
  const int t = threadIdx.x;
  const int r0 = blockIdx.x * 64;

  {
    const float4* Wg = (const float4*)W;
    float4* Wl4 = (float4*)Wl;
#pragma unroll
    for (int j = 0; j < (K * NC / 4) / TPB; ++j) Wl4[t + j * TPB] = Wg[t + j * TPB];
  }
  {
    int cq = t & 31, rb = t >> 5;
    float4 sc4 = *(const float4*)&bnst[cq * 4];
    float4 sh4 = *(const float4*)&bnst[K + cq * 4];
#pragma unroll
    for (int j = 0; j < 8; ++j) {
      int row = rb + j * 8;
      int r = r0 + row;
      float4 v = make_float4(0.f, 0.f, 0.f, 0.f);
      if (r < NN) {
        v = *(const float4*)&in[(size_t)r * 128 + cq * 4];
        v.x = fmaxf(fmaf(v.x, sc4.x, sh4.x), 0.f);
        v.y = fmaxf(fmaf(v.y, sc4.y, sh4.y), 0.f);
        v.z = fmaxf(fmaf(v.z, sc4.z, sh4.z), 0.f);
        v.w = fmaxf(fmaf(v.w, sc4.w, sh4.w), 0.f);
      }
      *(float4*)&Al[row * LDA + cq * 4] = v;
    }
  }
  __syncthreads();

  const int tx = t % TX, ty = t / TX;
  const int c0 = tx * 4;
  float4 b0 = *(const float4*)&bias[c0];
  float acc[RT][4];
#pragma unroll
  for (int i = 0; i < RT; ++i) {
    acc[i][0] = b0.x; acc[i][1] = b0.y; acc[i][2] = b0.z; acc[i][3] = b0.w;
  }
  const float* Ab = &Al[ty * RT * LDA];
#pragma unroll 4
  for (int k4 = 0; k4 < K / 4; ++k4) {
    float4 a[RT];
#pragma unroll
    for (int i = 0; i < RT; ++i) a[i] = *(const float4*)&Ab[i * LDA + k4 * 4];
#pragma unroll
    for (int kk = 0; kk < 4; ++kk) {
      float4 b = *(const float4*)&Wl[(k4 * 4 + kk) * NC + c0];
#pragma unroll
      for (int i = 0; i < RT; ++i) {
        float av = (&a[i].x)[kk];
        acc[i][0] = fmaf(av, b.x, acc[i][0]);
        acc[i][1] = fmaf(av, b.y, acc[i][1]);
        acc[i][2] = fmaf(av, b.z, acc[i][2]);
        acc[i][3] = fmaf(av, b.w, acc[i][3]);
      }
    }
  }
  float s[4] = {0.f, 0.f, 0.f, 0.f}, q[4] = {0.f, 0.f, 0.f, 0.f};
#pragma unroll
  for (int i = 0; i < RT; ++i) {
    int r = r0 + ty * RT + i;
    if (r < NN) {
      float ox = fmaxf(acc[i][0], 0.f), oy = fmaxf(acc[i][1], 0.f);
      float oz = fmaxf(acc[i][2], 0.f), ow = fmaxf(acc[i][3], 0.f);
      if constexpr (OUT_BF16) {
        ushort4 o = make_ushort4(f2bf(ox), f2bf(oy), f2bf(oz), f2bf(ow));
        *(ushort4*)&((unsigned short*)outp)[(size_t)r * NC + c0] = o;
      } else {
        *(float4*)&((float*)outp)[(size_t)r * NC + c0] = make_float4(ox, oy, oz, ow);
      }
      if constexpr (STATS) {
        s[0] += ox; q[0] += ox * ox;
        s[1] += oy; q[1] += oy * oy;
        s[2] += oz; q[2] += oz * oz;
        s[3] += ow; q[3] += ow * ow;
      }
    }
  }
  if constexpr (STATS) {
    __syncthreads();
    float* Sl = Al;
#pragma unroll
    for (int j = 0; j < 4; ++j) {
      Sl[ty * NC + c0 + j] = s[j];
      Sl[TY * NC + ty * NC + c0 + j] = q[j];
    }
    __syncthreads();
    if (t < NC) {
      float ss = 0.f, qq = 0.f;
#pragma unroll
      for (int g = 0; g < TY; ++g) {
        ss += Sl[g * NC + t];
        qq += Sl[TY * NC + g * NC + t];
      }
      partials[blockIdx.x * 2 * NC + t] = ss;
      partials[blockIdx.x * 2 * NC + NC + t] = qq;
    }
  }
}

// Fold partials across NBLK_G block-rows. 512 threads, G=TPB_FIN/C groups;
// CONSTANT trip count + unroll-8 => ~16 loads in flight per thread (the r7
// version's runtime-start loop defeated unrolling -> 2 loads in flight ->
// 108us latency-serialized). LDS tree-fold, emit [scale C | shift C].
template <int C>
__global__ __launch_bounds__(TPB_FIN) void k_finalize(const float* __restrict__ partials,
                                                      const float* __restrict__ gamma,
                                                      const float* __restrict__ beta,
                                                      float* __restrict__ out) {
  constexpr int G = TPB_FIN / C;       // 4 (C=128) or 8 (C=64)
  constexpr int IT = NBLK_G / G;       // 196 or 98 — compile-time constant
  __shared__ float lds[2 * TPB_FIN];
  const int c = threadIdx.x % C, g = threadIdx.x / C;
  const float* p = partials + g * 2 * C + c;
  float s = 0.f, s2 = 0.f;
#pragma unroll 8
  for (int bb = 0; bb < IT; ++bb) {
    s += p[(size_t)bb * G * 2 * C];
    s2 += p[(size_t)bb * G * 2 * C + C];
  }
  lds[threadIdx.x] = s;
  lds[TPB_FIN + threadIdx.x] = s2;
  __syncthreads();
  if (g == 0) {
#pragma unroll
    for (int k = 1; k < G; ++k) {
      s += lds[k * C + c];
      s2 += lds[TPB_FIN + k * C + c];
    }
    float invN = 1.0f / NN;
    float mu = s * invN;
    float var = s2 * invN - mu * mu;
    float rs = rsqrtf(var + BN_EPS) * gamma[c];
    out[c] = rs;
    out[C + c] = beta[c] - mu * rs;
  }
}

// one BLOCK per graph: 4 waves stride the contiguous row range, LDS-reduce.
__global__ void k_poolseg(const float* __restrict__ h, const int* __restrict__ batch,
                          float* __restrict__ g) {
  __shared__ float lds[TPB];
  int gi = blockIdx.x;
  int lane = threadIdx.x & 63, w = threadIdx.x >> 6;
  int a = 0, b = NN;
  while (a < b) { int m = (a + b) >> 1; if (batch[m] < gi) a = m + 1; else b = m; }
  int lo = a;
  b = NN;
  while (a < b) { int m = (a + b) >> 1; if (batch[m] < gi + 1) a = m + 1; else b = m; }
  int hi = a;
  float acc = 0.f;
  for (int n = lo + w; n < hi; n += 4) acc += h[(size_t)n * 64 + lane];
  lds[threadIdx.x] = acc;
  __syncthreads();
  if (w == 0)
    g[gi * 64 + lane] = lds[lane] + lds[64 + lane] + lds[128 + lane] + lds[192 + lane];
}

// out[512,10] = relu(g @ Wh1 + bh1) @ Wh2 + bh2 ; thread per graph
__global__ void k_head(const float* __restrict__ g, const float* __restrict__ Wh1,
                       const float* __restrict__ bh1, const float* __restrict__ Wh2,
                       const float* __restrict__ bh2, float* __restrict__ out) {
  __shared__ float W1l[64 * 32], W2l[32 * 10], b1l[32], b2l[10];
  for (int t = threadIdx.x; t < 64 * 32; t += TPB) W1l[t] = Wh1[t];
  for (int t = threadIdx.x; t < 320; t += TPB) W2l[t] = Wh2[t];
  if (threadIdx.x < 32) b1l[threadIdx.x] = bh1[threadIdx.x];
  if (threadIdx.x < 10) b2l[threadIdx.x] = bh2[threadIdx.x];
  __syncthreads();
  int gi = blockIdx.x * TPB + threadIdx.x;
  if (gi >= NG) return;
  float hid[32];
#pragma unroll
  for (int j = 0; j < 32; ++j) hid[j] = b1l[j];
  for (int k = 0; k < 64; ++k) {
    float gv = g[gi * 64 + k];
#pragma unroll
    for (int j = 0; j < 32; ++j) hid[j] += gv * W1l[k * 32 + j];
  }
  float o[10];
#pragma unroll
  for (int j = 0; j < 10; ++j) o[j] = b2l[j];
#pragma unroll
  for (int k = 0; k < 32; ++k) {
    float hv = fmaxf(hid[k], 0.f);
#pragma unroll
    for (int j = 0; j < 10; ++j) o[j] += hv * W2l[k * 10 + j];
  }
  for (int j = 0; j < 10; ++j) out[gi * 10 + j] = o[j];
}

extern "C" void kernel_launch(void* const* d_in, const int* in_sizes, int n_in,
                              void* d_out, int out_size, void* d_ws, size_t ws_size,
                              hipStream_t stream) {
  const int* x = (const int*)d_in[0];
  const int* ei = (const int*)d_in[1];
  const int* batch = (const int*)d_in[2];
  const float* emb = (const float*)d_in[3];
  const float* W1 = (const float*)d_in[4];
  const float* b1 = (const float*)d_in[5];
  const float* g1 = (const float*)d_in[6];
  const float* bt1 = (const float*)d_in[7];
  const float* W2 = (const float*)d_in[8];
  const float* b2 = (const float*)d_in[9];
  const float* gbn = (const float*)d_in[10];
  const float* bbn = (const float*)d_in[11];
  const float* Wh1 = (const float*)d_in[12];
  const float* bh1 = (const float*)d_in[13];
  const float* Wh2 = (const float*)d_in[14];
  const float* bh2 = (const float*)d_in[15];
  float* out = (float*)d_out;

  const int* e_src = ei;
  const int* e_dst = ei + NE;

  char* ws = (char*)d_ws;
  size_t off = 0;
  auto alloc = [&](size_t bytes) -> void* {
    void* p = ws + off;
    off = (off + bytes + 255) & ~(size_t)255;
    return p;
  };
  float* h = (float*)alloc((size_t)NN * 64 * 4);  // layer-3 output (f32)
  unsigned short* h_bf = (unsigned short*)alloc((size_t)NN * 64 * 2);  // layers 0-2
  float* z = (float*)alloc((size_t)NN * 64 * 4);
  float* z2 = (float*)alloc((size_t)NN * 128 * 4);
  int* srcs = (int*)alloc((size_t)NE * 4);
  int* row_ptr = (int*)alloc((size_t)(NN + 1) * 4);
  int* incl = (int*)alloc((size_t)NN * 4);
  int* btot = (int*)alloc(256 * 4);
  float* g = (float*)alloc((size_t)NG * 64 * 4);
  float* partials = (float*)alloc((size_t)NBLK_G * 256 * 4);
  float* statsL = (float*)alloc(4 * 256 * 4);
  float* statsH = (float*)alloc(3 * 128 * 4);
  int* counts = (int*)alloc((size_t)NN * 4);
  int* fill_pos = (int*)alloc((size_t)NN * 4);
  int zero_words = (int)(((char*)fill_pos - (char*)counts) / 4) + NN;

  int gz = (zero_words + TPB - 1) / TPB;
  k_zero<<<gz, TPB, 0, stream>>>(counts, zero_words);

  k_hist<<<EDGE_BLKS, TPB, 0, stream>>>(e_dst, counts);

  int nScanBlocks = (NN + TPB - 1) / TPB;
  k_scan1<<<nScanBlocks, TPB, 0, stream>>>(counts, incl, btot);
  k_scan2<<<1, TPB, 0, stream>>>(btot, nScanBlocks);
  int gScan3 = (NN + 1 + TPB - 1) / TPB;
  k_scan3<<<gScan3, TPB, 0, stream>>>(incl, btot, row_ptr);
  k_fill<<<FILL_P * EDGE_BLKS, TPB, 0, stream>>>(e_src, e_dst, row_ptr, fill_pos, srcs);

  int gAgg = (NN * 64 + TPB - 1) / TPB;  // 12500 (wave per node)

  for (int i = 0; i < 4; ++i) {
    const float* W1i = W1 + (size_t)i * 64 * 128;
    const float* b1i = b1 + (size_t)i * 128;
    const float* g1i = g1 + (size_t)i * 128;
    const float* bt1i = bt1 + (size_t)i * 128;
    const float* W2i = W2 + (size_t)i * 128 * 64;
    const float* b2i = b2 + (size_t)i * 64;
    float* stL = statsL + (size_t)i * 256;

    if (i == 0)
      k_aggregate0<<<gAgg, TPB, 0, stream>>>(x, emb, row_ptr, srcs, z);
    else
      k_aggregate_bf<<<gAgg, TPB, 0, stream>>>(h_bf, row_ptr, srcs,
                                               statsH + (size_t)(i - 1) * 128, z);

    k_gemm1<<<NBLK_G, TPB, 0, stream>>>(z, W1i, b1i, z2, partials);
    k_finalize<128><<<1, TPB_FIN, 0, stream>>>(partials, g1i, bt1i, stL);

    if (i < 3) {
      float* stH = statsH + (size_t)i * 128;
      k_gemm2<true, true><<<NBLK_G, TPB, 0, stream>>>(z2, W2i, b2i, stL, h_bf, partials);
      k_finalize<64><<<1, TPB_FIN, 0, stream>>>(partials, gbn + (size_t)i * 64,
                                                bbn + (size_t)i * 64, stH);
    } else {
      k_gemm2<false, false><<<NBLK_G, TPB, 0, stream>>>(z2, W2i, b2i, stL, h, partials);
    }
  }

  k_poolseg<<<NG, TPB, 0, stream>>>(h, batch, g);
  k_head<<<(NG + TPB - 1) / TPB, TPB, 0, stream>>>(g, Wh1, bh1, Wh2, bh2, out);
}

// Round 9
// 497.903 us; speedup vs baseline: 2.4117x; 1.0283x over previous
//
#include <hip/hip_runtime.h>

#define NN 50000
#define NE 800000
#define NG 512
#define TPB 256
#define BN_EPS 1e-5f
#define NBLK_G 784      // GEMM grid: ceil(NN/64)=782, padded to 784 so finalize
                        // trip count is a compile-time constant
#define EDGE_BLKS 3125  // NE/TPB exactly
#define TPB_FIN 512

__device__ __forceinline__ float bf2f(unsigned u) {  // low 16 bits = bf16
  return __uint_as_float(u << 16);
}
__device__ __forceinline__ unsigned f2bf(float f) {
  unsigned u = __float_as_uint(f);
  u += 0x7FFFu + ((u >> 16) & 1u);  // round-to-nearest-even
  return u >> 16;
}

__global__ void k_zero(int* __restrict__ p, int n) {
  int i = blockIdx.x * TPB + threadIdx.x;
  if (i < n) p[i] = 0;
}

__global__ void k_hist(const int* __restrict__ dst, int* __restrict__ counts) {
  int e = blockIdx.x * TPB + threadIdx.x;
  if (e < NE) atomicAdd(&counts[dst[e]], 1);
}

__global__ void k_scan1(const int* __restrict__ counts, int* __restrict__ incl,
                        int* __restrict__ btot) {
  __shared__ int lds[TPB];
  int i = blockIdx.x * TPB + threadIdx.x;
  int v = (i < NN) ? counts[i] : 0;
  lds[threadIdx.x] = v;
  __syncthreads();
  for (int off = 1; off < TPB; off <<= 1) {
    int t = (threadIdx.x >= off) ? lds[threadIdx.x - off] : 0;
    __syncthreads();
    lds[threadIdx.x] += t;
    __syncthreads();
  }
  if (i < NN) incl[i] = lds[threadIdx.x];
  if (threadIdx.x == TPB - 1) btot[blockIdx.x] = lds[TPB - 1];
}

__global__ void k_scan2(int* __restrict__ btot, int nb) {
  __shared__ int lds[TPB];
  int t = (threadIdx.x < nb) ? btot[threadIdx.x] : 0;
  int own = t;
  lds[threadIdx.x] = t;
  __syncthreads();
  for (int off = 1; off < TPB; off <<= 1) {
    int u = (threadIdx.x >= off) ? lds[threadIdx.x - off] : 0;
    __syncthreads();
    lds[threadIdx.x] += u;
    __syncthreads();
  }
  btot[threadIdx.x] = lds[threadIdx.x] - own;
}

__global__ void k_scan3(const int* __restrict__ incl, const int* __restrict__ btot,
                        int* __restrict__ row_ptr) {
  int i = blockIdx.x * TPB + threadIdx.x;
  if (i == 0) row_ptr[0] = 0;
  if (i < NN) row_ptr[i + 1] = incl[i] + btot[i >> 8];
}

// counting-sort fill; packs src index (16b) + its embedding id x[src] (5b)
// into one uint so the aggregates never gather x.
__global__ void k_fill(const int* __restrict__ src, const int* __restrict__ dst,
                       const int* __restrict__ x, const int* __restrict__ row_ptr,
                       int* __restrict__ fill_pos, unsigned* __restrict__ srcs) {
  int e = blockIdx.x * TPB + threadIdx.x;  // EDGE_BLKS*TPB == NE exactly
  int d = dst[e];
  int pos = row_ptr[d] + atomicAdd(&fill_pos[d], 1);
  int s = src[e];
  srcs[pos] = (unsigned)s | ((unsigned)x[s] << 16);
}

// Layer-0 aggregate: h implicit = emb[x[n]] (emb 8KB -> L1-hot). Wave per node,
// 32 lanes x 2 features (float2 emb loads); halves take even/odd edges,
// shfl_xor(32) combines; writes z as packed bf16 pairs.
__global__ void k_aggregate0(const int* __restrict__ x, const float* __restrict__ emb,
                             const int* __restrict__ row_ptr,
                             const unsigned* __restrict__ srcs,
                             unsigned* __restrict__ zb) {
  int wid = (blockIdx.x * TPB + threadIdx.x) >> 6;
  int lane = threadIdx.x & 63;
  if (wid >= NN) return;
  int half = lane >> 5, l = lane & 31;
  int beg = row_ptr[wid], end = row_ptr[wid + 1];
  float a0 = 0.f, a1 = 0.f;
  if (half == 0) {
    float2 ev = *(const float2*)&emb[x[wid] * 64 + 2 * l];
    a0 = ev.x;
    a1 = ev.y;
  }
  int e = beg + half;
  for (; e + 6 < end; e += 8) {
    unsigned p0 = srcs[e], p1 = srcs[e + 2], p2 = srcs[e + 4], p3 = srcs[e + 6];
    float2 v0 = *(const float2*)&emb[(p0 >> 16) * 64 + 2 * l];
    float2 v1 = *(const float2*)&emb[(p1 >> 16) * 64 + 2 * l];
    float2 v2 = *(const float2*)&emb[(p2 >> 16) * 64 + 2 * l];
    float2 v3 = *(const float2*)&emb[(p3 >> 16) * 64 + 2 * l];
    a0 += (v0.x + v1.x) + (v2.x + v3.x);
    a1 += (v0.y + v1.y) + (v2.y + v3.y);
  }
  for (; e < end; e += 2) {
    float2 v = *(const float2*)&emb[(srcs[e] >> 16) * 64 + 2 * l];
    a0 += v.x;
    a1 += v.y;
  }
  a0 += __shfl_xor(a0, 32);
  a1 += __shfl_xor(a1, 32);
  if (half == 0) zb[(size_t)wid * 32 + l] = f2bf(a0) | (f2bf(a1) << 16);
}

// Layers 1..3 aggregate over bf16 h, BN affine of prev layer folded in:
//   z = sc*(h_self + sum h_src) + (1+deg)*sh   -> packed bf16
__global__ void k_aggregate_bf(const unsigned* __restrict__ h_bf,
                               const int* __restrict__ row_ptr,
                               const unsigned* __restrict__ srcs,
                               const float* __restrict__ bnst,
                               unsigned* __restrict__ zb) {
  int wid = (blockIdx.x * TPB + threadIdx.x) >> 6;
  int lane = threadIdx.x & 63;
  if (wid >= NN) return;
  int half = lane >> 5, l = lane & 31;
  int beg = row_ptr[wid], end = row_ptr[wid + 1];
  float a0 = 0.f, a1 = 0.f;
  if (half == 0) {
    unsigned u = h_bf[(size_t)wid * 32 + l];
    a0 = bf2f(u & 0xFFFF);
    a1 = bf2f(u >> 16);
  }
  int e = beg + half;
  for (; e + 6 < end; e += 8) {
    int s0 = srcs[e] & 0xFFFF, s1 = srcs[e + 2] & 0xFFFF;
    int s2 = srcs[e + 4] & 0xFFFF, s3 = srcs[e + 6] & 0xFFFF;
    unsigned u0 = h_bf[(size_t)s0 * 32 + l];
    unsigned u1 = h_bf[(size_t)s1 * 32 + l];
    unsigned u2 = h_bf[(size_t)s2 * 32 + l];
    unsigned u3 = h_bf[(size_t)s3 * 32 + l];
    a0 += (bf2f(u0 & 0xFFFF) + bf2f(u1 & 0xFFFF)) +
          (bf2f(u2 & 0xFFFF) + bf2f(u3 & 0xFFFF));
    a1 += (bf2f(u0 >> 16) + bf2f(u1 >> 16)) + (bf2f(u2 >> 16) + bf2f(u3 >> 16));
  }
  for (; e < end; e += 2) {
    unsigned u = h_bf[(size_t)(srcs[e] & 0xFFFF) * 32 + l];
    a0 += bf2f(u & 0xFFFF);
    a1 += bf2f(u >> 16);
  }
  a0 += __shfl_xor(a0, 32);
  a1 += __shfl_xor(a1, 32);
  if (half == 0) {
    float2 scv = *(const float2*)&bnst[2 * l];
    float2 shv = *(const float2*)&bnst[64 + 2 * l];
    float d1 = (float)(1 + end - beg);
    float zv0 = fmaf(scv.x, a0, d1 * shv.x);
    float zv1 = fmaf(scv.y, a1, d1 * shv.y);
    zb[(size_t)wid * 32 + l] = f2bf(zv0) | (f2bf(zv1) << 16);
  }
}

// GEMM1: z2[N,128] = z[N,64] @ W[64,128] + b1 (z bf16 in, z2 bf16 out),
// with per-block f32 column stats of z2.
__global__ __launch_bounds__(TPB) void k_gemm1(const unsigned short* __restrict__ zb,
                                               const float* __restrict__ W,
                                               const float* __restrict__ bias,
                                               unsigned short* __restrict__ z2b,
                                               float* __restrict__ partials) {
  constexpr int K = 64, NC = 128, LDA = 68;
  constexpr int TX = 32, TY = 8, RT = 8;
  __shared__ float Al[64 * LDA];
  __shared__ float Wl[K * NC];
  const int t = threadIdx.x;
  const int r0 = blockIdx.x * 64;

  {
    const float4* Wg = (const float4*)W;
    float4* Wl4 = (float4*)Wl;
#pragma unroll
    for (int j = 0; j < (K * NC / 4) / TPB; ++j) Wl4[t + j * TPB] = Wg[t + j * TPB];
  }
#pragma unroll
  for (int j = 0; j < 4; ++j) {
    int qi = t + j * TPB;
    int row = qi >> 4, cq = qi & 15;
    int r = r0 + row;
    float4 v = make_float4(0.f, 0.f, 0.f, 0.f);
    if (r < NN) {
      uint2 u = *(const uint2*)&zb[(size_t)r * 64 + cq * 4];
      v = make_float4(bf2f(u.x & 0xFFFF), bf2f(u.x >> 16), bf2f(u.y & 0xFFFF),
                      bf2f(u.y >> 16));
    }
    *(float4*)&Al[row * LDA + cq * 4] = v;
  }
  __syncthreads();

  const int tx = t % TX, ty = t / TX;
  const int c0 = tx * 4;
  float4 b0 = *(const float4*)&bias[c0];
  float acc[RT][4];
#pragma unroll
  for (int i = 0; i < RT; ++i) {
    acc[i][0] = b0.x; acc[i][1] = b0.y; acc[i][2] = b0.z; acc[i][3] = b0.w;
  }
  const float* Ab = &Al[ty * RT * LDA];
#pragma unroll 4
  for (int k4 = 0; k4 < K / 4; ++k4) {
    float4 a[RT];
#pragma unroll
    for (int i = 0; i < RT; ++i) a[i] = *(const float4*)&Ab[i * LDA + k4 * 4];
#pragma unroll
    for (int kk = 0; kk < 4; ++kk) {
      float4 b = *(const float4*)&Wl[(k4 * 4 + kk) * NC + c0];
#pragma unroll
      for (int i = 0; i < RT; ++i) {
        float av = (&a[i].x)[kk];
        acc[i][0] = fmaf(av, b.x, acc[i][0]);
        acc[i][1] = fmaf(av, b.y, acc[i][1]);
        acc[i][2] = fmaf(av, b.z, acc[i][2]);
        acc[i][3] = fmaf(av, b.w, acc[i][3]);
      }
    }
  }
  float s[4] = {0.f, 0.f, 0.f, 0.f}, q[4] = {0.f, 0.f, 0.f, 0.f};
#pragma unroll
  for (int i = 0; i < RT; ++i) {
    int r = r0 + ty * RT + i;
    if (r < NN) {
      uint2 o;
      o.x = f2bf(acc[i][0]) | (f2bf(acc[i][1]) << 16);
      o.y = f2bf(acc[i][2]) | (f2bf(acc[i][3]) << 16);
      *(uint2*)&z2b[(size_t)r * NC + c0] = o;
      s[0] += acc[i][0]; q[0] += acc[i][0] * acc[i][0];
      s[1] += acc[i][1]; q[1] += acc[i][1] * acc[i][1];
      s[2] += acc[i][2]; q[2] += acc[i][2] * acc[i][2];
      s[3] += acc[i][3]; q[3] += acc[i][3] * acc[i][3];
    }
  }
  __syncthreads();
  float* Sl = Al;  // 2*TY*NC = 2048 floats
#pragma unroll
  for (int j = 0; j < 4; ++j) {
    Sl[ty * NC + c0 + j] = s[j];
    Sl[TY * NC + ty * NC + c0 + j] = q[j];
  }
  __syncthreads();
  if (t < NC) {
    float ss = 0.f, qq = 0.f;
#pragma unroll
    for (int g = 0; g < TY; ++g) {
      ss += Sl[g * NC + t];
      qq += Sl[TY * NC + g * NC + t];
    }
    partials[blockIdx.x * 2 * NC + t] = ss;
    partials[blockIdx.x * 2 * NC + NC + t] = qq;
  }
}

// GEMM2: h[N,64] = relu( relu(bn1(z2)) @ W[128,64] + b2 ), z2 bf16 in.
template <bool STATS, bool OUT_BF16>
__global__ __launch_bounds__(TPB) void k_gemm2(const unsigned short* __restrict__ z2b,
                                               const float* __restrict__ W,
                                               const float* __restrict__ bias,
                                               const float* __restrict__ bnst,
                                               void* __restrict__ outp,
                                               float* __restrict__ partials) {
  constexpr int K = 128, NC = 64, LDA = 128;
  constexpr int TX = 16, TY = 16, RT = 4;
  __shared__ float Al[64 * LDA];
  __shared__ float Wl[K * NC];
  const int t = threadIdx.x;
  const int r0 = blockIdx.x * 64;

  {
    const float4* Wg = (const float4*)W;
    float4* Wl4 = (float4*)Wl;
#pragma unroll
    for (int j = 0; j < (K * NC / 4) / TPB; ++j) Wl4[t + j * TPB] = Wg[t + j * TPB];
  }
  {
    int cq = t & 15, rb = t >> 4;  // 16 col-groups of 8, 16 row-lanes
    float4 scA = *(const float4*)&bnst[cq * 8];
    float4 scB = *(const float4*)&bnst[cq * 8 + 4];
    float4 shA = *(const float4*)&bnst[K + cq * 8];
    float4 shB = *(const float4*)&bnst[K + cq * 8 + 4];
#pragma unroll
    for (int j = 0; j < 4; ++j) {
      int row = rb + j * 16;
      int r = r0 + row;
      float4 vA = make_float4(0.f, 0.f, 0.f, 0.f), vB = vA;
      if (r < NN) {
        uint4 u = *(const uint4*)&z2b[(size_t)r * 128 + cq * 8];
        vA = make_float4(bf2f(u.x & 0xFFFF), bf2f(u.x >> 16), bf2f(u.y & 0xFFFF),
                         bf2f(u.y >> 16));
        vB = make_float4(bf2f(u.z & 0xFFFF), bf2f(u.z >> 16), bf2f(u.w & 0xFFFF),
                         bf2f(u.w >> 16));
        vA.x = fmaxf(fmaf(vA.x, scA.x, shA.x), 0.f);
        vA.y = fmaxf(fmaf(vA.y, scA.y, shA.y), 0.f);
        vA.z = fmaxf(fmaf(vA.z, scA.z, shA.z), 0.f);
        vA.w = fmaxf(fmaf(vA.w, scA.w, shA.w), 0.f);
        vB.x = fmaxf(fmaf(vB.x, scB.x, shB.x), 0.f);
        vB.y = fmaxf(fmaf(vB.y, scB.y, shB.y), 0.f);
        vB.z = fmaxf(fmaf(vB.z, scB.z, shB.z), 0.f);
        vB.w = fmaxf(fmaf(vB.w, scB.w, shB.w), 0.f);
      }
      *(float4*)&Al[row * LDA + cq * 8] = vA;
      *(float4*)&Al[row * LDA + cq * 8 + 4] = vB;
    }
  }
  __syncthreads();

  const int tx = t % TX, ty = t / TX;
  const int c0 = tx * 4;
  float4 b0 = *(const float4*)&bias[c0];
  float acc[RT][4];
#pragma unroll
  for (int i = 0; i < RT; ++i) {
    acc[i][0] = b0.x; acc[i][1] = b0.y; acc[i][2] = b0.z; acc[i][3] = b0.w;
  }
  const float* Ab = &Al[ty * RT * LDA];
#pragma unroll 4
  for (int k4 = 0; k4 < K / 4; ++k4) {
    float4 a[RT];
#pragma unroll
    for (int i = 0; i < RT; ++i) a[i] = *(const float4*)&Ab[i * LDA + k4 * 4];
#pragma unroll
    for (int kk = 0; kk < 4; ++kk) {
      float4 b = *(const float4*)&Wl[(k4 * 4 + kk) * NC + c0];
#pragma unroll
      for (int i = 0; i < RT; ++i) {
        float av = (&a[i].x)[kk];
        acc[i][0] = fmaf(av, b.x, acc[i][0]);
        acc[i][1] = fmaf(av, b.y, acc[i][1]);
        acc[i][2] = fmaf(av, b.z, acc[i][2]);
        acc[i][3] = fmaf(av, b.w, acc[i][3]);
      }
    }
  }
  float s[4] = {0.f, 0.f, 0.f, 0.f}, q[4] = {0.f, 0.f, 0.f, 0.f};
#pragma unroll
  for (int i = 0; i < RT; ++i) {
    int r = r0 + ty * RT + i;
    if (r < NN) {
      float ox = fmaxf(acc[i][0], 0.f), oy = fmaxf(acc[i][1], 0.f);
      float oz = fmaxf(acc[i][2], 0.f), ow = fmaxf(acc[i][3], 0.f);
      if constexpr (OUT_BF16) {
        uint2 o;
        o.x = f2bf(ox) | (f2bf(oy) << 16);
        o.y = f2bf(oz) | (f2bf(ow) << 16);
        *(uint2*)&((unsigned short*)outp)[(size_t)r * NC + c0] = o;
      } else {
        *(float4*)&((float*)outp)[(size_t)r * NC + c0] = make_float4(ox, oy, oz, ow);
      }
      if constexpr (STATS) {
        s[0] += ox; q[0] += ox * ox;
        s[1] += oy; q[1] += oy * oy;
        s[2] += oz; q[2] += oz * oz;
        s[3] += ow; q[3] += ow * ow;
      }
    }
  }
  if constexpr (STATS) {
    __syncthreads();
    float* Sl = Al;
#pragma unroll
    for (int j = 0; j < 4; ++j) {
      Sl[ty * NC + c0 + j] = s[j];
      Sl[TY * NC + ty * NC + c0 + j] = q[j];
    }
    __syncthreads();
    if (t < NC) {
      float ss = 0.f, qq = 0.f;
#pragma unroll
      for (int g = 0; g < TY; ++g) {
        ss += Sl[g * NC + t];
        qq += Sl[TY * NC + g * NC + t];
      }
      partials[blockIdx.x * 2 * NC + t] = ss;
      partials[blockIdx.x * 2 * NC + NC + t] = qq;
    }
  }
}

// Fold partials: constant trip count + unroll-8 (r8 fix), LDS tree-fold.
template <int C>
__global__ __launch_bounds__(TPB_FIN) void k_finalize(const float* __restrict__ partials,
                                                      const float* __restrict__ gamma,
                                                      const float* __restrict__ beta,
                                                      float* __restrict__ out) {
  constexpr int G = TPB_FIN / C;
  constexpr int IT = NBLK_G / G;
  __shared__ float lds[2 * TPB_FIN];
  const int c = threadIdx.x % C, g = threadIdx.x / C;
  const float* p = partials + g * 2 * C + c;
  float s = 0.f, s2 = 0.f;
#pragma unroll 8
  for (int bb = 0; bb < IT; ++bb) {
    s += p[(size_t)bb * G * 2 * C];
    s2 += p[(size_t)bb * G * 2 * C + C];
  }
  lds[threadIdx.x] = s;
  lds[TPB_FIN + threadIdx.x] = s2;
  __syncthreads();
  if (g == 0) {
#pragma unroll
    for (int k = 1; k < G; ++k) {
      s += lds[k * C + c];
      s2 += lds[TPB_FIN + k * C + c];
    }
    float invN = 1.0f / NN;
    float mu = s * invN;
    float var = s2 * invN - mu * mu;
    float rs = rsqrtf(var + BN_EPS) * gamma[c];
    out[c] = rs;
    out[C + c] = beta[c] - mu * rs;
  }
}

// one BLOCK per graph: 4 waves stride the contiguous row range, LDS-reduce.
__global__ void k_poolseg(const float* __restrict__ h, const int* __restrict__ batch,
                          float* __restrict__ g) {
  __shared__ float lds[TPB];
  int gi = blockIdx.x;
  int lane = threadIdx.x & 63, w = threadIdx.x >> 6;
  int a = 0, b = NN;
  while (a < b) { int m = (a + b) >> 1; if (batch[m] < gi) a = m + 1; else b = m; }
  int lo = a;
  b = NN;
  while (a < b) { int m = (a + b) >> 1; if (batch[m] < gi + 1) a = m + 1; else b = m; }
  int hi = a;
  float acc = 0.f;
  for (int n = lo + w; n < hi; n += 4) acc += h[(size_t)n * 64 + lane];
  lds[threadIdx.x] = acc;
  __syncthreads();
  if (w == 0)
    g[gi * 64 + lane] = lds[lane] + lds[64 + lane] + lds[128 + lane] + lds[192 + lane];
}

// out[512,10] = relu(g @ Wh1 + bh1) @ Wh2 + bh2 ; thread per graph
__global__ void k_head(const float* __restrict__ g, const float* __restrict__ Wh1,
                       const float* __restrict__ bh1, const float* __restrict__ Wh2,
                       const float* __restrict__ bh2, float* __restrict__ out) {
  __shared__ float W1l[64 * 32], W2l[32 * 10], b1l[32], b2l[10];
  for (int t = threadIdx.x; t < 64 * 32; t += TPB) W1l[t] = Wh1[t];
  for (int t = threadIdx.x; t < 320; t += TPB) W2l[t] = Wh2[t];
  if (threadIdx.x < 32) b1l[threadIdx.x] = bh1[threadIdx.x];
  if (threadIdx.x < 10) b2l[threadIdx.x] = bh2[threadIdx.x];
  __syncthreads();
  int gi = blockIdx.x * TPB + threadIdx.x;
  if (gi >= NG) return;
  float hid[32];
#pragma unroll
  for (int j = 0; j < 32; ++j) hid[j] = b1l[j];
  for (int k = 0; k < 64; ++k) {
    float gv = g[gi * 64 + k];
#pragma unroll
    for (int j = 0; j < 32; ++j) hid[j] += gv * W1l[k * 32 + j];
  }
  float o[10];
#pragma unroll
  for (int j = 0; j < 10; ++j) o[j] = b2l[j];
#pragma unroll
  for (int k = 0; k < 32; ++k) {
    float hv = fmaxf(hid[k], 0.f);
#pragma unroll
    for (int j = 0; j < 10; ++j) o[j] += hv * W2l[k * 10 + j];
  }
  for (int j = 0; j < 10; ++j) out[gi * 10 + j] = o[j];
}

extern "C" void kernel_launch(void* const* d_in, const int* in_sizes, int n_in,
                              void* d_out, int out_size, void* d_ws, size_t ws_size,
                              hipStream_t stream) {
  const int* x = (const int*)d_in[0];
  const int* ei = (const int*)d_in[1];
  const int* batch = (const int*)d_in[2];
  const float* emb = (const float*)d_in[3];
  const float* W1 = (const float*)d_in[4];
  const float* b1 = (const float*)d_in[5];
  const float* g1 = (const float*)d_in[6];
  const float* bt1 = (const float*)d_in[7];
  const float* W2 = (const float*)d_in[8];
  const float* b2 = (const float*)d_in[9];
  const float* gbn = (const float*)d_in[10];
  const float* bbn = (const float*)d_in[11];
  const float* Wh1 = (const float*)d_in[12];
  const float* bh1 = (const float*)d_in[13];
  const float* Wh2 = (const float*)d_in[14];
  const float* bh2 = (const float*)d_in[15];
  float* out = (float*)d_out;

  const int* e_src = ei;
  const int* e_dst = ei + NE;

  char* ws = (char*)d_ws;
  size_t off = 0;
  auto alloc = [&](size_t bytes) -> void* {
    void* p = ws + off;
    off = (off + bytes + 255) & ~(size_t)255;
    return p;
  };
  float* h = (float*)alloc((size_t)NN * 64 * 4);             // layer-3 output (f32)
  unsigned* h_bf = (unsigned*)alloc((size_t)NN * 64 * 2);    // layers 0-2 (bf16 packed)
  unsigned* zb = (unsigned*)alloc((size_t)NN * 64 * 2);      // z (bf16 packed)
  unsigned short* z2b = (unsigned short*)alloc((size_t)NN * 128 * 2);  // z2 (bf16)
  unsigned* srcs = (unsigned*)alloc((size_t)NE * 4);
  int* row_ptr = (int*)alloc((size_t)(NN + 1) * 4);
  int* incl = (int*)alloc((size_t)NN * 4);
  int* btot = (int*)alloc(256 * 4);
  float* g = (float*)alloc((size_t)NG * 64 * 4);
  float* partials = (float*)alloc((size_t)NBLK_G * 256 * 4);
  float* statsL = (float*)alloc(4 * 256 * 4);
  float* statsH = (float*)alloc(3 * 128 * 4);
  int* counts = (int*)alloc((size_t)NN * 4);
  int* fill_pos = (int*)alloc((size_t)NN * 4);
  int zero_words = (int)(((char*)fill_pos - (char*)counts) / 4) + NN;

  int gz = (zero_words + TPB - 1) / TPB;
  k_zero<<<gz, TPB, 0, stream>>>(counts, zero_words);

  k_hist<<<EDGE_BLKS, TPB, 0, stream>>>(e_dst, counts);

  int nScanBlocks = (NN + TPB - 1) / TPB;
  k_scan1<<<nScanBlocks, TPB, 0, stream>>>(counts, incl, btot);
  k_scan2<<<1, TPB, 0, stream>>>(btot, nScanBlocks);
  int gScan3 = (NN + 1 + TPB - 1) / TPB;
  k_scan3<<<gScan3, TPB, 0, stream>>>(incl, btot, row_ptr);
  k_fill<<<EDGE_BLKS, TPB, 0, stream>>>(e_src, e_dst, x, row_ptr, fill_pos, srcs);

  int gAgg = (NN * 64 + TPB - 1) / TPB;  // 12500 (wave per node)

  for (int i = 0; i < 4; ++i) {
    const float* W1i = W1 + (size_t)i * 64 * 128;
    const float* b1i = b1 + (size_t)i * 128;
    const float* g1i = g1 + (size_t)i * 128;
    const float* bt1i = bt1 + (size_t)i * 128;
    const float* W2i = W2 + (size_t)i * 128 * 64;
    const float* b2i = b2 + (size_t)i * 64;
    float* stL = statsL + (size_t)i * 256;

    if (i == 0)
      k_aggregate0<<<gAgg, TPB, 0, stream>>>(x, emb, row_ptr, srcs, zb);
    else
      k_aggregate_bf<<<gAgg, TPB, 0, stream>>>(h_bf, row_ptr, srcs,
                                               statsH + (size_t)(i - 1) * 128, zb);

    k_gemm1<<<NBLK_G, TPB, 0, stream>>>((const unsigned short*)zb, W1i, b1i, z2b, partials);
    k_finalize<128><<<1, TPB_FIN, 0, stream>>>(partials, g1i, bt1i, stL);

    if (i < 3) {
      float* stH = statsH + (size_t)i * 128;
      k_gemm2<true, true><<<NBLK_G, TPB, 0, stream>>>(z2b, W2i, b2i, stL, h_bf, partials);
      k_finalize<64><<<1, TPB_FIN, 0, stream>>>(partials, gbn + (size_t)i * 64,
                                                bbn + (size_t)i * 64, stH);
    } else {
      k_gemm2<false, false><<<NBLK_G, TPB, 0, stream>>>(z2b, W2i, b2i, stL, h, partials);
    }
  }

  k_poolseg<<<NG, TPB, 0, stream>>>(h, batch, g);
  k_head<<<(NG + TPB - 1) / TPB, TPB, 0, stream>>>(g, Wh1, bh1, Wh2, bh2, out);
}